// Round 8
// baseline (227.151 us; speedup 1.0000x reference)
//
#include <hip/hip_runtime.h>

typedef _Float16 f16x8 __attribute__((ext_vector_type(8)));
typedef unsigned short u16x8 __attribute__((ext_vector_type(8)));
typedef float f32x4  __attribute__((ext_vector_type(4)));
typedef unsigned short u16;

#define T_SEQ 2048
#define C_DIM 1024
#define NH 16
#define HS 64
#define S_SETS 1023
#define S_PAD 1024
// q pre-scale: (1/sqrt(64)) * log2(e)  -> logits live in log2 domain,
// so softmax uses raw v_exp_f32 (2^x) with no per-element multiply.
#define SCALE2 0.18033688011112042f
#define NEG_BIG -1e30f
#define MSENT  -50000.0f   // finite sentinel: below any real logit, but
                           // exp2(NEG_BIG - MSENT) still underflows to 0

#define GLB(p) ((const __attribute__((address_space(1))) void*)(p))
#define LDS(p) ((__attribute__((address_space(3))) void*)(p))

__device__ __forceinline__ u16 f2h(float f) {
    _Float16 h = (_Float16)f;
    return __builtin_bit_cast(unsigned short, h);
}
__device__ __forceinline__ float h2f(u16 u) {
    _Float16 h = __builtin_bit_cast(_Float16, u);
    return (float)h;
}
__device__ __forceinline__ float exp2h(float x) {   // 2^x, single v_exp_f32
    float r; asm("v_exp_f32 %0, %1" : "=v"(r) : "v"(x)); return r;
}
__device__ __forceinline__ float log2h(float x) {   // log2(x)
    float r; asm("v_log_f32 %0, %1" : "=v"(r) : "v"(x)); return r;
}
__device__ __forceinline__ f32x4 mfmah(f16x8 a, f16x8 b, f32x4 c) {
    return __builtin_amdgcn_mfma_f32_16x16x32_f16(a, b, c, 0, 0, 0);
}

// -------- Kernel 0: fp32 -> fp16, all three inputs in one launch -------------
__global__ __launch_bounds__(256) void conv_all(const float* __restrict__ x,
                                                const float* __restrict__ wa,
                                                const float* __restrict__ wp,
                                                u16* __restrict__ x16,
                                                u16* __restrict__ wa16,
                                                u16* __restrict__ wp16) {
    int i = blockIdx.x * 256 + threadIdx.x;
    const float* src; u16* dst; int off;
    if (i < 1048576)              { src = x;  dst = x16;  off = i; }
    else if (i < 1048576 + 786432){ src = wa; dst = wa16; off = i - 1048576; }
    else                          { src = wp; dst = wp16; off = i - (1048576 + 786432); }
    float4 f = ((const float4*)src)[off];
    ushort4 o;
    o.x = f2h(f.x); o.y = f2h(f.y); o.z = f2h(f.z); o.w = f2h(f.w);
    ((ushort4*)dst)[off] = o;
}

// -------- Kernel 1: qkv = x @ W_attn^T, fp16 MFMA, 128x128 tile --------------
// 2-phase prefetch; q -> fp16 PRE-SCALED by SCALE2 (log2-domain); k,v -> fp16.
// Epilogue: C-tile staged in LDS (aliased over staging bufs) -> u16x8 vector
// stores. Each block writes exactly ONE of q/k/v (nt>>3) and 2 heads (nt&7).
// Dynamic LDS: max(staging 32768, Cs 128*132*2 = 33792) = 33792 bytes.
__global__ __launch_bounds__(256) void gemm_qkv16(const u16* __restrict__ x16,
                                                  const u16* __restrict__ wa16,
                                                  u16* __restrict__ q16,
                                                  u16* __restrict__ k16,
                                                  u16* __restrict__ v16) {
    extern __shared__ u16 smem[];
    u16* As0 = smem;            // [128*32]
    u16* As1 = smem + 4096;
    u16* Bs0 = smem + 8192;
    u16* Bs1 = smem + 12288;
    int tid = threadIdx.x, wv = tid >> 6, lane = tid & 63;
    int lm = lane & 15, quad = lane >> 4;
    int mt = blockIdx.x / 24, nt = blockIdx.x % 24;
    int wm = wv >> 1, wn = wv & 1;
    int m_off = wm * 64, n_off = wn * 64;

    const u16* gsrc;
    u16 *ldst0, *ldst1;
    int half = wv & 1;
    if (wv < 2) { gsrc = x16  + (size_t)(mt * 128 + half * 64) * C_DIM;
                  ldst0 = As0 + half * 2048; ldst1 = As1 + half * 2048; }
    else        { gsrc = wa16 + (size_t)(nt * 128 + half * 64) * C_DIM;
                  ldst0 = Bs0 + half * 2048; ldst1 = Bs1 + half * 2048; }
    int srow = lane >> 2, scol = (lane & 3) * 8;

    f32x4 acc[4][4];
    #pragma unroll
    for (int i = 0; i < 4; ++i)
        #pragma unroll
        for (int j = 0; j < 4; ++j) acc[i][j] = (f32x4){0.f, 0.f, 0.f, 0.f};

    #pragma unroll
    for (int i = 0; i < 4; ++i)
        __builtin_amdgcn_global_load_lds(
            GLB(gsrc + (size_t)(i * 16 + srow) * C_DIM + scol),
            LDS(ldst0 + i * 512), 16, 0, 0);
    __syncthreads();

    for (int k0 = 0, it = 0; k0 < C_DIM; k0 += 32, ++it) {
        const u16* Ab = (it & 1) ? As1 : As0;
        const u16* Bb = (it & 1) ? Bs1 : Bs0;
        if (k0 + 32 < C_DIM) {
            u16* nd = (it & 1) ? ldst0 : ldst1;
            #pragma unroll
            for (int i = 0; i < 4; ++i)
                __builtin_amdgcn_global_load_lds(
                    GLB(gsrc + (size_t)(i * 16 + srow) * C_DIM + k0 + 32 + scol),
                    LDS(nd + i * 512), 16, 0, 0);
        }
        f16x8 af[4], bf[4];
        #pragma unroll
        for (int i = 0; i < 4; ++i) {
            af[i] = *(const f16x8*)(Ab + (m_off + i * 16 + lm) * 32 + quad * 8);
            bf[i] = *(const f16x8*)(Bb + (n_off + i * 16 + lm) * 32 + quad * 8);
        }
        #pragma unroll
        for (int mi = 0; mi < 4; ++mi)
            #pragma unroll
            for (int ni = 0; ni < 4; ++ni)
                acc[mi][ni] = mfmah(af[mi], bf[ni], acc[mi][ni]);
        __syncthreads();
    }

    // epilogue: stage fp16 C-tile in LDS (aliases staging bufs; all reads done)
    u16* Cs = smem;                       // [128][132] u16
    int wq = nt >> 3;                     // 0=q, 1=k, 2=v (block-uniform)
    int hb = (nt & 7) * 2;                // first of the 2 heads this block owns
    #pragma unroll
    for (int mi = 0; mi < 4; ++mi)
        #pragma unroll
        for (int ni = 0; ni < 4; ++ni) {
            int nl = n_off + ni * 16 + lm;
            #pragma unroll
            for (int reg = 0; reg < 4; ++reg) {
                int ml = m_off + mi * 16 + quad * 4 + reg;
                float val = acc[mi][ni][reg];
                Cs[ml * 132 + nl] = f2h(wq == 0 ? val * SCALE2 : val);
            }
        }
    __syncthreads();
    u16* outp = wq == 0 ? q16 : (wq == 1 ? k16 : v16);
    int r = tid & 127, hf = tid >> 7;     // row, head-half
    int m = mt * 128 + r, b_ = m >> 11, t_ = m & 2047;
    u16* dst = outp + (((size_t)(b_ * NH + hb + hf)) * T_SEQ + t_) * HS;
    const u16* sr = Cs + r * 132 + hf * 64;
    #pragma unroll
    for (int i = 0; i < 8; ++i)
        *(u16x8*)(dst + i * 8) = *(const u16x8*)(sr + i * 8);
}

// -------- Kernel 2: hierarchical set sums (fp16 in) -> fp16 outputs ----------
// Level-0 loads vectorized: per task (sg, h) 4x u16x8 (16B) loads, vector
// K16 store; f32 tree in LDS unchanged.
__global__ __launch_bounds__(256) void set_sums(const u16* __restrict__ k16,
                                                const u16* __restrict__ v16,
                                                u16* __restrict__ K16,
                                                u16* __restrict__ VT16) {
    int bh  = blockIdx.x;
    int src = blockIdx.y >> 2;
    int dc  = blockIdx.y & 3;
    int tid = threadIdx.x;
    __shared__ float lv0[512 * 16];
    __shared__ float lv1[256 * 16];
    const u16* sp = src ? v16 : k16;
    u16* op = src ? VT16 : K16;
    int dbase = dc * 16;
    // zero the padded set row/col 1023 (staged unmasked by the attn kernel)
    if (tid < 16) {
        int d = dbase + tid;
        size_t o = src ? ((size_t)bh * HS + d) * S_PAD + 1023
                       : ((size_t)bh * S_PAD + 1023) * HS + d;
        op[o] = 0;
    }
    // level 0: 1024 tasks (sg in [0,512), h in {0,1}), 4 per thread
    for (int task = tid; task < 1024; task += 256) {
        int sg = task >> 1, h = task & 1;
        int d0 = dbase + h * 8;
        const u16* p = sp + ((size_t)bh * T_SEQ + sg * 4) * HS + d0;
        u16x8 r0 = *(const u16x8*)(p);
        u16x8 r1 = *(const u16x8*)(p + HS);
        u16x8 r2 = *(const u16x8*)(p + 2 * HS);
        u16x8 r3 = *(const u16x8*)(p + 3 * HS);
        float s[8];
        #pragma unroll
        for (int e = 0; e < 8; ++e) {
            s[e] = h2f(r0[e]) + h2f(r1[e]) + h2f(r2[e]) + h2f(r3[e]);
            lv0[sg * 16 + h * 8 + e] = s[e];
        }
        if (src) {
            #pragma unroll
            for (int e = 0; e < 8; ++e)
                op[((size_t)bh * HS + d0 + e) * S_PAD + sg] = f2h(s[e]);
        } else {
            u16x8 ov;
            #pragma unroll
            for (int e = 0; e < 8; ++e) ov[e] = f2h(s[e]);
            *(u16x8*)(op + ((size_t)bh * S_PAD + sg) * HS + d0) = ov;
        }
    }
    __syncthreads();
    int nsets = 256, offset = 512, lvl = 1;
    while (nsets >= 1) {
        float* sbuf = (lvl & 1) ? lv0 : lv1;
        float* dbuf = (lvl & 1) ? lv1 : lv0;
        for (int idx = tid; idx < nsets * 16; idx += 256) {
            int i = idx >> 4, dd = idx & 15, d = dbase + dd;
            float s = sbuf[(2 * i) * 16 + dd] + sbuf[(2 * i + 1) * 16 + dd];
            dbuf[i * 16 + dd] = s;
            int so = offset + i;
            size_t o = src ? ((size_t)bh * HS + d) * S_PAD + so
                           : ((size_t)bh * S_PAD + so) * HS + d;
            op[o] = f2h(s);
        }
        __syncthreads();
        offset += nsets; nsets >>= 1; lvl++;
    }
}

// -------- Kernel 3: flash attention over set-halves ---------------------------
// grid (32, 32, 2): x = bh (XCD-pinned), y = query-group pair, z = set-half.
// log2-domain softmax (q pre-scaled by log2e): exp = raw v_exp_f32.
// mrun starts at finite MSENT so masked logits (NEG_BIG) underflow to 0
// in exp2 with no guard compare. Zero-fill of P only when PV partner active.
__global__ __launch_bounds__(256) void attn_flash16(const u16* __restrict__ q16,
                                                    const u16* __restrict__ K16,
                                                    const u16* __restrict__ VT16,
                                                    u16* __restrict__ Opart,
                                                    float* __restrict__ LSEpart) {
    int bh = blockIdx.x;
    int half = blockIdx.z;
    int tid = threadIdx.x, wv = tid >> 6, lane = tid & 63;
    int lm = lane & 15, quad = lane >> 4;
    int tgrp = (wv < 2) ? (32 * blockIdx.y) : (2016 - 32 * blockIdx.y);
    int t0w = tgrp + (wv & 1) * 16;
    int twmax = t0w + 15;
    int sbase = half * 512;

    __shared__ u16 Ks[2][64 * 64];    // dbuf K chunk fp16, XOR-swizzled (16 KB)
    __shared__ u16 Pbuf[4][16 * 72];  // per-wave P fp16 (9.2 KB)
    __shared__ u16 rtab[512];         // mask boundary r(s) for this half (1 KB)

    const u16* qg = q16 + ((size_t)bh * T_SEQ + t0w + lm) * HS;
    f16x8 a0 = *(const f16x8*)(qg + quad * 8);
    f16x8 a1 = *(const f16x8*)(qg + 32 + quad * 8);

    // build r-table once (2 entries/thread); covered by the staging barrier
    #pragma unroll
    for (int i = tid; i < 512; i += 256) {
        int s = sbase + i;
        unsigned rv = 0xFFFFu;
        if (s < S_SETS) {
            int e = S_SETS - s;
            int l = __clz(e) - 22;          // level: L = 4<<l
            int i0 = s - (1024 - (1024 >> l));
            rv = (unsigned)((i0 + 1) * (4 << l) - 1);
        }
        rtab[i] = (u16)rv;
    }

    f32x4 O[4];
    #pragma unroll
    for (int i = 0; i < 4; ++i) O[i] = (f32x4){0.f, 0.f, 0.f, 0.f};
    f32x4 mrun = (f32x4){MSENT, MSENT, MSENT, MSENT};
    f32x4 lsum = (f32x4){0.f, 0.f, 0.f, 0.f};

    u16* Pw = &Pbuf[wv][0];
    const u16* vb  = VT16 + (size_t)bh * HS * S_PAD;
    const u16* kbh = K16  + ((size_t)bh * S_PAD + sbase) * HS;

    // gload_lds staging: wave wv covers rows [wv*16, wv*16+16) per chunk.
    // Global source pre-swizzled; LINEAR LDS dest.
    int l8 = lane >> 3;
    int lg = (lane & 7) ^ l8;
    const u16* gsw = kbh + (size_t)(wv * 16 + l8) * HS + lg * 8;

    // prologue: stage chunk 0 into buf 0
    __builtin_amdgcn_global_load_lds(GLB(gsw),       LDS(&Ks[0][wv * 1024]),       16, 0, 0);
    __builtin_amdgcn_global_load_lds(GLB(gsw + 512), LDS(&Ks[0][wv * 1024 + 512]), 16, 0, 0);
    __syncthreads();

    for (int c = 0; c < 8; ++c) {
        int cur = c & 1;
        int s0 = sbase + c * 64;
        const u16* Ksb = &Ks[cur][0];

        // issue next chunk's DMA into the alternate buffer
        if (c < 7) {
            const u16* gn = gsw + (size_t)(c + 1) * 4096;
            __builtin_amdgcn_global_load_lds(GLB(gn),       LDS(&Ks[cur ^ 1][wv * 1024]),       16, 0, 0);
            __builtin_amdgcn_global_load_lds(GLB(gn + 512), LDS(&Ks[cur ^ 1][wv * 1024 + 512]), 16, 0, 0);
        }

        // mask boundaries for this chunk's 4 s-tiles (from LDS table)
        int r4[4];
        #pragma unroll
        for (int st = 0; st < 4; ++st) r4[st] = rtab[c * 64 + st * 16 + lm];

        // QK^T: 4 s-tiles, masked, wave-uniform skip
        unsigned flags = 0;
        f32x4 lt[4];
        #pragma unroll
        for (int st = 0; st < 4; ++st) {
            int r = r4[st];
            unsigned long long bal = __ballot(r <= twmax);
            if (bal) {
                flags |= 1u << st;
                int sl = st * 16 + lm, sx = sl & 7;
                f16x8 b0 = *(const f16x8*)(Ksb + sl * 64 + ((quad ^ sx) << 3));
                f16x8 b1 = *(const f16x8*)(Ksb + sl * 64 + (((4 + quad) ^ sx) << 3));
                f32x4 a = (f32x4){0.f, 0.f, 0.f, 0.f};
                a = mfmah(a0, b0, a);
                a = mfmah(a1, b1, a);
                #pragma unroll
                for (int reg = 0; reg < 4; ++reg) {
                    int t = t0w + quad * 4 + reg;
                    lt[st][reg] = (t >= r) ? a[reg] : NEG_BIG;
                }
            }
        }

        if (flags) {
            // per-lane chunk max (reused by both gate and slow path)
            f32x4 mc = (f32x4){NEG_BIG, NEG_BIG, NEG_BIG, NEG_BIG};
            #pragma unroll
            for (int st = 0; st < 4; ++st)
                if ((flags >> st) & 1u)
                    #pragma unroll
                    for (int reg = 0; reg < 4; ++reg)
                        mc[reg] = fmaxf(mc[reg], lt[st][reg]);
            bool need = false;
            #pragma unroll
            for (int reg = 0; reg < 4; ++reg)
                need |= mc[reg] > mrun[reg] + 8.f;
            if (__ballot(need)) {
                // slow path: cross-lane max + rescale (log2 domain)
                #pragma unroll
                for (int off = 1; off < 16; off <<= 1)
                    #pragma unroll
                    for (int reg = 0; reg < 4; ++reg)
                        mc[reg] = fmaxf(mc[reg], __shfl_xor(mc[reg], off));
                #pragma unroll
                for (int reg = 0; reg < 4; ++reg) {
                    float mnew = fmaxf(mrun[reg], mc[reg]);
                    float alpha = exp2h(mrun[reg] - mnew);
                    lsum[reg] *= alpha;
                    #pragma unroll
                    for (int dt = 0; dt < 4; ++dt) O[dt][reg] *= alpha;
                    mrun[reg] = mnew;
                }
            }
            // fast path: P = 2^(lt - mrun); masked lt underflows to exactly 0
            #pragma unroll
            for (int st = 0; st < 4; ++st) {
                if ((flags >> st) & 1u) {
                    #pragma unroll
                    for (int reg = 0; reg < 4; ++reg) {
                        float p = exp2h(lt[st][reg] - mrun[reg]);
                        lsum[reg] += p;
                        Pw[(quad * 4 + reg) * 72 + st * 16 + lm] = f2h(p);
                    }
                } else if ((flags >> (st ^ 1)) & 1u) {
                    // zeros only needed when the PV 32-set partner is active
                    #pragma unroll
                    for (int reg = 0; reg < 4; ++reg)
                        Pw[(quad * 4 + reg) * 72 + st * 16 + lm] = 0;
                }
            }

            // P @ V chunk (skip fully-masked 32-set segments), V from L2
            #pragma unroll
            for (int kc = 0; kc < 2; ++kc) {
                if (!((flags >> (2 * kc)) & 3u)) continue;
                f16x8 afr = *(const f16x8*)(Pw + lm * 72 + kc * 32 + quad * 8);
                #pragma unroll
                for (int dt = 0; dt < 4; ++dt) {
                    size_t vo = (size_t)(dt * 16 + lm) * S_PAD + s0 + kc * 32 + quad * 8;
                    f16x8 bv = *(const f16x8*)(vb + vo);
                    O[dt] = mfmah(afr, bv, O[dt]);
                }
            }
        }

        if (c < 7) __syncthreads();
    }

    // single cross-lane sum reduce (outside the chunk loop)
    #pragma unroll
    for (int off = 1; off < 16; off <<= 1)
        #pragma unroll
        for (int reg = 0; reg < 4; ++reg) lsum[reg] += __shfl_xor(lsum[reg], off);

    // store partials: O/l (f16) and LSE = m + log2(l) (log2 domain, f32)
    u16* Ob = Opart + ((size_t)half * 32 + bh) * T_SEQ * HS;
    float* Lb = LSEpart + ((size_t)half * 32 + bh) * T_SEQ;
    #pragma unroll
    for (int reg = 0; reg < 4; ++reg) {
        int t = t0w + quad * 4 + reg;
        float inv = lsum[reg] > 0.f ? 1.f / lsum[reg] : 0.f;
        #pragma unroll
        for (int dt = 0; dt < 4; ++dt)
            Ob[(size_t)t * HS + dt * 16 + lm] = f2h(O[dt][reg] * inv);
        if (lm == 0)
            Lb[t] = lsum[reg] > 0.f ? mrun[reg] + log2h(lsum[reg]) : NEG_BIG;
    }
}

// -------- Kernel 3b: merge two set-half partials + tail, write att16 ---------
// grid (512, 32), 256 thr: wave = one (bh,t) row, lane = dim d.
// All LSE values and the tail logit are in the log2 domain.
__global__ __launch_bounds__(256) void attn_combine(const u16* __restrict__ q16,
                                                    const u16* __restrict__ k16,
                                                    const u16* __restrict__ v16,
                                                    const u16* __restrict__ Opart,
                                                    const float* __restrict__ LSEpart,
                                                    u16* __restrict__ att16) {
    int bh = blockIdx.y;
    int wv = threadIdx.x >> 6, d = threadIdx.x & 63;
    int t = blockIdx.x * 4 + wv;
    size_t row = (size_t)bh * T_SEQ + t;

    float lse0 = LSEpart[row];
    float lse1 = LSEpart[(size_t)32 * T_SEQ + row];

    // tail: K_tail/V_tail over last (t%4)+1 positions; q16 pre-scaled (log2e)
    int len = (t & 3) + 1;
    const u16* kp = k16 + row * HS + d;
    const u16* vp = v16 + row * HS + d;
    float kt = 0.f, vt = 0.f;
    for (int j = 0; j < len; ++j) { kt += h2f(kp[-j * HS]); vt += h2f(vp[-j * HS]); }
    float tl = h2f(q16[row * HS + d]) * kt;
    #pragma unroll
    for (int off = 1; off < 64; off <<= 1) tl += __shfl_xor(tl, off);

    float mf = fmaxf(fmaxf(lse0, lse1), tl);
    float w0 = exp2h(lse0 - mf), w1 = exp2h(lse1 - mf), wt = exp2h(tl - mf);
    float inv = 1.f / (w0 + w1 + wt);
    float o0 = h2f(Opart[row * HS + d]);
    float o1 = h2f(Opart[(size_t)32 * T_SEQ * HS + row * HS + d]);
    float val = (w0 * o0 + w1 * o1 + wt * vt) * inv;

    int b_ = bh >> 4, h_ = bh & 15;
    att16[((size_t)b_ * T_SEQ + t) * C_DIM + h_ * HS + d] = f2h(val);
}

// -------- Kernel 4: out = attout @ W_proj^T, fp16 MFMA, 128x64 tile ----------
// Grid 512 blocks (2 blocks/CU, 8 waves/CU) vs prior 256 (1/CU, 1 wave/SIMD).
// 2-phase prefetch; wave = 64x32 output (acc[4][2]).
__global__ __launch_bounds__(256) void gemm_proj16(const u16* __restrict__ a_,
                                                   const u16* __restrict__ w,
                                                   float* __restrict__ out) {
    __shared__ u16 As[2][128 * 32];
    __shared__ u16 Bs[2][64 * 32];
    int tid = threadIdx.x, wv = tid >> 6, lane = tid & 63;
    int lm = lane & 15, quad = lane >> 4;
    int mt = blockIdx.x >> 4, nt = blockIdx.x & 15;   // 32 x 16
    int wm = wv >> 1, wn = wv & 1;
    int m_off = wm * 64, n_off = wn * 32;

    const u16* gsrc;
    u16 *ldst0, *ldst1;
    int nstage;
    if (wv < 2) { gsrc = a_ + (size_t)(mt * 128 + wv * 64) * C_DIM;
                  ldst0 = &As[0][wv * 2048]; ldst1 = &As[1][wv * 2048]; nstage = 4; }
    else        { int bhalf = wv - 2;
                  gsrc = w + (size_t)(nt * 64 + bhalf * 32) * C_DIM;
                  ldst0 = &Bs[0][bhalf * 1024]; ldst1 = &Bs[1][bhalf * 1024]; nstage = 2; }
    int srow = lane >> 2, scol = (lane & 3) * 8;

    f32x4 acc[4][2];
    #pragma unroll
    for (int i = 0; i < 4; ++i)
        #pragma unroll
        for (int j = 0; j < 2; ++j) acc[i][j] = (f32x4){0.f, 0.f, 0.f, 0.f};

    for (int i = 0; i < nstage; ++i)
        __builtin_amdgcn_global_load_lds(
            GLB(gsrc + (size_t)(i * 16 + srow) * C_DIM + scol),
            LDS(ldst0 + i * 512), 16, 0, 0);
    __syncthreads();

    for (int k0 = 0, it = 0; k0 < C_DIM; k0 += 32, ++it) {
        const u16* Ab = (it & 1) ? &As[1][0] : &As[0][0];
        const u16* Bb = (it & 1) ? &Bs[1][0] : &Bs[0][0];
        if (k0 + 32 < C_DIM) {
            u16* nd = (it & 1) ? ldst0 : ldst1;
            for (int i = 0; i < nstage; ++i)
                __builtin_amdgcn_global_load_lds(
                    GLB(gsrc + (size_t)(i * 16 + srow) * C_DIM + k0 + 32 + scol),
                    LDS(nd + i * 512), 16, 0, 0);
        }
        f16x8 af[4], bf[2];
        #pragma unroll
        for (int i = 0; i < 4; ++i)
            af[i] = *(const f16x8*)(Ab + (m_off + i * 16 + lm) * 32 + quad * 8);
        #pragma unroll
        for (int i = 0; i < 2; ++i)
            bf[i] = *(const f16x8*)(Bb + (n_off + i * 16 + lm) * 32 + quad * 8);
        #pragma unroll
        for (int mi = 0; mi < 4; ++mi)
            #pragma unroll
            for (int ni = 0; ni < 2; ++ni)
                acc[mi][ni] = mfmah(af[mi], bf[ni], acc[mi][ni]);
        __syncthreads();
    }

    #pragma unroll
    for (int mi = 0; mi < 4; ++mi)
        #pragma unroll
        for (int ni = 0; ni < 2; ++ni) {
            int n = nt * 64 + n_off + ni * 16 + lm;
            #pragma unroll
            for (int reg = 0; reg < 4; ++reg) {
                int m = mt * 128 + m_off + mi * 16 + quad * 4 + reg;
                out[(size_t)m * C_DIM + n] = acc[mi][ni][reg];
            }
        }
}

extern "C" void kernel_launch(void* const* d_in, const int* in_sizes, int n_in,
                              void* d_out, int out_size, void* d_ws, size_t ws_size,
                              hipStream_t stream) {
    const float* x     = (const float*)d_in[0];
    const float* Wattn = (const float*)d_in[1];
    const float* Wproj = (const float*)d_in[2];
    float* out = (float*)d_out;
    char* ws = (char*)d_ws;
    // workspace layout (61.3 MB), with time-multiplexed overlays:
    //   [0, 16.78MB): x16(8MB)+wa16(6.29MB) during qkv -> Opart during attn
    u16*  Opart = (u16*)(ws + 0);            // 16,777,216 [attn partials, 2 halves]
    u16*  x16   = (u16*)(ws + 0);            //  8,388,608 (dead after gemm_qkv16)
    u16*  wa16  = (u16*)(ws + 8388608);      //  6,291,456 (dead after gemm_qkv16)
    u16*  q16   = (u16*)(ws + 16777216);     //  8,388,608 (pre-scaled, log2 dom.)
    u16*  k16   = (u16*)(ws + 25165824);     //  8,388,608
    u16*  v16   = (u16*)(ws + 33554432);     //  8,388,608
    u16*  K16   = (u16*)(ws + 41943040);     //  4,194,304
    u16*  VT16  = (u16*)(ws + 46137344);     //  4,194,304
    u16*  att16 = (u16*)(ws + 50331648);     //  8,388,608
    float* LSE  = (float*)(ws + 58720256);   //    524,288
    u16*  wp16  = (u16*)(ws + 59244544);     //  2,097,152  (end 61,341,696)

    hipLaunchKernelGGL(conv_all, dim3(8192), dim3(256), 0, stream,
                       x, Wattn, Wproj, x16, wa16, wp16);
    hipLaunchKernelGGL(gemm_qkv16, dim3(768), dim3(256), 33792, stream,
                       x16, wa16, q16, k16, v16);
    hipLaunchKernelGGL(set_sums, dim3(32, 8), dim3(256), 0, stream, k16, v16, K16, VT16);
    hipLaunchKernelGGL(attn_flash16, dim3(32, 32, 2), dim3(256), 0, stream,
                       q16, K16, VT16, Opart, LSE);
    hipLaunchKernelGGL(attn_combine, dim3(512, 32), dim3(256), 0, stream,
                       q16, k16, v16, Opart, LSE, att16);
    hipLaunchKernelGGL(gemm_proj16, dim3(512), dim3(256), 0, stream, att16, wp16, out);
}

// Round 10
// 220.741 us; speedup vs baseline: 1.0290x; 1.0290x over previous
//
#include <hip/hip_runtime.h>

typedef _Float16 f16x8 __attribute__((ext_vector_type(8)));
typedef unsigned short u16x8 __attribute__((ext_vector_type(8)));
typedef float f32x4  __attribute__((ext_vector_type(4)));
typedef unsigned short u16;

#define T_SEQ 2048
#define C_DIM 1024
#define NH 16
#define HS 64
#define S_SETS 1023
#define S_PAD 1024
// q pre-scale: (1/sqrt(64)) * log2(e)  -> logits live in log2 domain,
// so softmax uses raw v_exp_f32 (2^x) with no per-element multiply.
#define SCALE2 0.18033688011112042f
#define NEG_BIG -1e30f
#define MSENT  -50000.0f   // finite sentinel: below any real logit, but
                           // exp2(NEG_BIG - MSENT) still underflows to 0

#define GLB(p) ((const __attribute__((address_space(1))) void*)(p))
#define LDS(p) ((__attribute__((address_space(3))) void*)(p))

__device__ __forceinline__ u16 f2h(float f) {
    _Float16 h = (_Float16)f;
    return __builtin_bit_cast(unsigned short, h);
}
__device__ __forceinline__ float h2f(u16 u) {
    _Float16 h = __builtin_bit_cast(_Float16, u);
    return (float)h;
}
__device__ __forceinline__ float exp2h(float x) {   // 2^x, single v_exp_f32
    float r; asm("v_exp_f32 %0, %1" : "=v"(r) : "v"(x)); return r;
}
__device__ __forceinline__ float log2h(float x) {   // log2(x)
    float r; asm("v_log_f32 %0, %1" : "=v"(r) : "v"(x)); return r;
}
__device__ __forceinline__ f32x4 mfmah(f16x8 a, f16x8 b, f32x4 c) {
    return __builtin_amdgcn_mfma_f32_16x16x32_f16(a, b, c, 0, 0, 0);
}

// -------- Kernel 0: fp32 -> fp16, all three inputs in one launch -------------
__global__ __launch_bounds__(256) void conv_all(const float* __restrict__ x,
                                                const float* __restrict__ wa,
                                                const float* __restrict__ wp,
                                                u16* __restrict__ x16,
                                                u16* __restrict__ wa16,
                                                u16* __restrict__ wp16) {
    int i = blockIdx.x * 256 + threadIdx.x;
    const float* src; u16* dst; int off;
    if (i < 1048576)              { src = x;  dst = x16;  off = i; }
    else if (i < 1048576 + 786432){ src = wa; dst = wa16; off = i - 1048576; }
    else                          { src = wp; dst = wp16; off = i - (1048576 + 786432); }
    float4 f = ((const float4*)src)[off];
    ushort4 o;
    o.x = f2h(f.x); o.y = f2h(f.y); o.z = f2h(f.z); o.w = f2h(f.w);
    ((ushort4*)dst)[off] = o;
}

// -------- Kernel 1: qkv = x @ W_attn^T, fp16 MFMA, 128x128 tile --------------
// 2-phase prefetch. MFMA operands SWAPPED (bf, af) so the acc reg dimension
// spans n: which/h become block-uniform and each (mi,ni) emits one ushort4
// (4 consecutive d) per thread -> 16 vector stores, no per-element branch.
// q -> fp16 PRE-SCALED by SCALE2 (log2-domain); k,v -> fp16.
__global__ __launch_bounds__(256) void gemm_qkv16(const u16* __restrict__ x16,
                                                  const u16* __restrict__ wa16,
                                                  u16* __restrict__ q16,
                                                  u16* __restrict__ k16,
                                                  u16* __restrict__ v16) {
    __shared__ u16 As[2][128 * 32];
    __shared__ u16 Bs[2][128 * 32];
    int tid = threadIdx.x, wv = tid >> 6, lane = tid & 63;
    int lm = lane & 15, quad = lane >> 4;
    int mt = blockIdx.x / 24, nt = blockIdx.x % 24;
    int wm = wv >> 1, wn = wv & 1;
    int m_off = wm * 64, n_off = wn * 64;

    const u16* gsrc;
    u16 *ldst0, *ldst1;
    int half = wv & 1;
    if (wv < 2) { gsrc = x16  + (size_t)(mt * 128 + half * 64) * C_DIM;
                  ldst0 = &As[0][half * 2048]; ldst1 = &As[1][half * 2048]; }
    else        { gsrc = wa16 + (size_t)(nt * 128 + half * 64) * C_DIM;
                  ldst0 = &Bs[0][half * 2048]; ldst1 = &Bs[1][half * 2048]; }
    int srow = lane >> 2, scol = (lane & 3) * 8;

    f32x4 acc[4][4];
    #pragma unroll
    for (int i = 0; i < 4; ++i)
        #pragma unroll
        for (int j = 0; j < 4; ++j) acc[i][j] = (f32x4){0.f, 0.f, 0.f, 0.f};

    #pragma unroll
    for (int i = 0; i < 4; ++i)
        __builtin_amdgcn_global_load_lds(
            GLB(gsrc + (size_t)(i * 16 + srow) * C_DIM + scol),
            LDS(ldst0 + i * 512), 16, 0, 0);
    __syncthreads();

    for (int k0 = 0, it = 0; k0 < C_DIM; k0 += 32, ++it) {
        const u16* Ab = (it & 1) ? &As[1][0] : &As[0][0];
        const u16* Bb = (it & 1) ? &Bs[1][0] : &Bs[0][0];
        if (k0 + 32 < C_DIM) {
            u16* nd = (it & 1) ? ldst0 : ldst1;
            #pragma unroll
            for (int i = 0; i < 4; ++i)
                __builtin_amdgcn_global_load_lds(
                    GLB(gsrc + (size_t)(i * 16 + srow) * C_DIM + k0 + 32 + scol),
                    LDS(nd + i * 512), 16, 0, 0);
        }
        f16x8 af[4], bf[4];
        #pragma unroll
        for (int i = 0; i < 4; ++i) {
            af[i] = *(const f16x8*)(Ab + (m_off + i * 16 + lm) * 32 + quad * 8);
            bf[i] = *(const f16x8*)(Bb + (n_off + i * 16 + lm) * 32 + quad * 8);
        }
        #pragma unroll
        for (int mi = 0; mi < 4; ++mi)
            #pragma unroll
            for (int ni = 0; ni < 4; ++ni)
                acc[mi][ni] = mfmah(bf[ni], af[mi], acc[mi][ni]);  // D[n][m]
        __syncthreads();
    }

    // epilogue: D[n][m] layout -> n = nt*128 + n_off + ni*16 + quad*4 + reg,
    // m = mt*128 + m_off + mi*16 + lm. 4 regs = 4 consecutive d (no head
    // crossing: n-tiles are 128-aligned), which = nt>>3 block-uniform.
    int wq = nt >> 3;
    u16* outp = wq == 0 ? q16 : (wq == 1 ? k16 : v16);
    float sc = wq == 0 ? SCALE2 : 1.0f;
    #pragma unroll
    for (int mi = 0; mi < 4; ++mi) {
        int m = mt * 128 + m_off + mi * 16 + lm;
        int b_ = m >> 11, t_ = m & 2047;
        #pragma unroll
        for (int ni = 0; ni < 4; ++ni) {
            int n = nt * 128 + n_off + ni * 16 + quad * 4;
            int h = (n >> 6) & 15, d = n & 63;
            size_t oi = (((size_t)(b_ * NH + h)) * T_SEQ + t_) * HS + d;
            ushort4 o;
            o.x = f2h(acc[mi][ni][0] * sc);
            o.y = f2h(acc[mi][ni][1] * sc);
            o.z = f2h(acc[mi][ni][2] * sc);
            o.w = f2h(acc[mi][ni][3] * sc);
            *(ushort4*)(outp + oi) = o;
        }
    }
}

// -------- Kernel 2: hierarchical set sums (fp16 in) -> fp16 outputs ----------
// Level-0 loads vectorized: per task (sg, h) 4x u16x8 (16B) loads, vector
// K16 store; f32 tree in LDS unchanged.
__global__ __launch_bounds__(256) void set_sums(const u16* __restrict__ k16,
                                                const u16* __restrict__ v16,
                                                u16* __restrict__ K16,
                                                u16* __restrict__ VT16) {
    int bh  = blockIdx.x;
    int src = blockIdx.y >> 2;
    int dc  = blockIdx.y & 3;
    int tid = threadIdx.x;
    __shared__ float lv0[512 * 16];
    __shared__ float lv1[256 * 16];
    const u16* sp = src ? v16 : k16;
    u16* op = src ? VT16 : K16;
    int dbase = dc * 16;
    // zero the padded set row/col 1023 (staged unmasked by the attn kernel)
    if (tid < 16) {
        int d = dbase + tid;
        size_t o = src ? ((size_t)bh * HS + d) * S_PAD + 1023
                       : ((size_t)bh * S_PAD + 1023) * HS + d;
        op[o] = 0;
    }
    // level 0: 1024 tasks (sg in [0,512), h in {0,1}), 4 per thread
    for (int task = tid; task < 1024; task += 256) {
        int sg = task >> 1, h = task & 1;
        int d0 = dbase + h * 8;
        const u16* p = sp + ((size_t)bh * T_SEQ + sg * 4) * HS + d0;
        u16x8 r0 = *(const u16x8*)(p);
        u16x8 r1 = *(const u16x8*)(p + HS);
        u16x8 r2 = *(const u16x8*)(p + 2 * HS);
        u16x8 r3 = *(const u16x8*)(p + 3 * HS);
        float s[8];
        #pragma unroll
        for (int e = 0; e < 8; ++e) {
            s[e] = h2f(r0[e]) + h2f(r1[e]) + h2f(r2[e]) + h2f(r3[e]);
            lv0[sg * 16 + h * 8 + e] = s[e];
        }
        if (src) {
            #pragma unroll
            for (int e = 0; e < 8; ++e)
                op[((size_t)bh * HS + d0 + e) * S_PAD + sg] = f2h(s[e]);
        } else {
            u16x8 ov;
            #pragma unroll
            for (int e = 0; e < 8; ++e) ov[e] = f2h(s[e]);
            *(u16x8*)(op + ((size_t)bh * S_PAD + sg) * HS + d0) = ov;
        }
    }
    __syncthreads();
    int nsets = 256, offset = 512, lvl = 1;
    while (nsets >= 1) {
        float* sbuf = (lvl & 1) ? lv0 : lv1;
        float* dbuf = (lvl & 1) ? lv1 : lv0;
        for (int idx = tid; idx < nsets * 16; idx += 256) {
            int i = idx >> 4, dd = idx & 15, d = dbase + dd;
            float s = sbuf[(2 * i) * 16 + dd] + sbuf[(2 * i + 1) * 16 + dd];
            dbuf[i * 16 + dd] = s;
            int so = offset + i;
            size_t o = src ? ((size_t)bh * HS + d) * S_PAD + so
                           : ((size_t)bh * S_PAD + so) * HS + d;
            op[o] = f2h(s);
        }
        __syncthreads();
        offset += nsets; nsets >>= 1; lvl++;
    }
}

// -------- Kernel 3: flash attention over set-halves ---------------------------
// grid (32, 32, 2): x = bh (XCD-pinned), y = query-group pair, z = set-half.
// log2-domain softmax; deferred-max; s_setprio(1) around MFMA clusters (T5:
// co-resident blocks sit at different chunk phases -> scheduler can favor
// the MFMA-issuing wave).
__global__ __launch_bounds__(256) void attn_flash16(const u16* __restrict__ q16,
                                                    const u16* __restrict__ K16,
                                                    const u16* __restrict__ VT16,
                                                    u16* __restrict__ Opart,
                                                    float* __restrict__ LSEpart) {
    int bh = blockIdx.x;
    int half = blockIdx.z;
    int tid = threadIdx.x, wv = tid >> 6, lane = tid & 63;
    int lm = lane & 15, quad = lane >> 4;
    int tgrp = (wv < 2) ? (32 * blockIdx.y) : (2016 - 32 * blockIdx.y);
    int t0w = tgrp + (wv & 1) * 16;
    int twmax = t0w + 15;
    int sbase = half * 512;

    __shared__ u16 Ks[2][64 * 64];    // dbuf K chunk fp16, XOR-swizzled (16 KB)
    __shared__ u16 Pbuf[4][16 * 72];  // per-wave P fp16 (9.2 KB)
    __shared__ u16 rtab[512];         // mask boundary r(s) for this half (1 KB)

    const u16* qg = q16 + ((size_t)bh * T_SEQ + t0w + lm) * HS;
    f16x8 a0 = *(const f16x8*)(qg + quad * 8);
    f16x8 a1 = *(const f16x8*)(qg + 32 + quad * 8);

    // build r-table once (2 entries/thread); covered by the staging barrier
    #pragma unroll
    for (int i = tid; i < 512; i += 256) {
        int s = sbase + i;
        unsigned rv = 0xFFFFu;
        if (s < S_SETS) {
            int e = S_SETS - s;
            int l = __clz(e) - 22;          // level: L = 4<<l
            int i0 = s - (1024 - (1024 >> l));
            rv = (unsigned)((i0 + 1) * (4 << l) - 1);
        }
        rtab[i] = (u16)rv;
    }

    f32x4 O[4];
    #pragma unroll
    for (int i = 0; i < 4; ++i) O[i] = (f32x4){0.f, 0.f, 0.f, 0.f};
    f32x4 mrun = (f32x4){MSENT, MSENT, MSENT, MSENT};
    f32x4 lsum = (f32x4){0.f, 0.f, 0.f, 0.f};

    u16* Pw = &Pbuf[wv][0];
    const u16* vb  = VT16 + (size_t)bh * HS * S_PAD;
    const u16* kbh = K16  + ((size_t)bh * S_PAD + sbase) * HS;

    // gload_lds staging: wave wv covers rows [wv*16, wv*16+16) per chunk.
    // Global source pre-swizzled; LINEAR LDS dest.
    int l8 = lane >> 3;
    int lg = (lane & 7) ^ l8;
    const u16* gsw = kbh + (size_t)(wv * 16 + l8) * HS + lg * 8;

    // prologue: stage chunk 0 into buf 0
    __builtin_amdgcn_global_load_lds(GLB(gsw),       LDS(&Ks[0][wv * 1024]),       16, 0, 0);
    __builtin_amdgcn_global_load_lds(GLB(gsw + 512), LDS(&Ks[0][wv * 1024 + 512]), 16, 0, 0);
    __syncthreads();

    for (int c = 0; c < 8; ++c) {
        int cur = c & 1;
        int s0 = sbase + c * 64;
        const u16* Ksb = &Ks[cur][0];

        // issue next chunk's DMA into the alternate buffer
        if (c < 7) {
            const u16* gn = gsw + (size_t)(c + 1) * 4096;
            __builtin_amdgcn_global_load_lds(GLB(gn),       LDS(&Ks[cur ^ 1][wv * 1024]),       16, 0, 0);
            __builtin_amdgcn_global_load_lds(GLB(gn + 512), LDS(&Ks[cur ^ 1][wv * 1024 + 512]), 16, 0, 0);
        }

        // mask boundaries for this chunk's 4 s-tiles (from LDS table)
        int r4[4];
        #pragma unroll
        for (int st = 0; st < 4; ++st) r4[st] = rtab[c * 64 + st * 16 + lm];

        // QK^T: 4 s-tiles, masked, wave-uniform skip
        unsigned flags = 0;
        f32x4 lt[4];
        #pragma unroll
        for (int st = 0; st < 4; ++st) {
            int r = r4[st];
            unsigned long long bal = __ballot(r <= twmax);
            if (bal) {
                flags |= 1u << st;
                int sl = st * 16 + lm, sx = sl & 7;
                f16x8 b0 = *(const f16x8*)(Ksb + sl * 64 + ((quad ^ sx) << 3));
                f16x8 b1 = *(const f16x8*)(Ksb + sl * 64 + (((4 + quad) ^ sx) << 3));
                __builtin_amdgcn_s_setprio(1);
                f32x4 a = (f32x4){0.f, 0.f, 0.f, 0.f};
                a = mfmah(a0, b0, a);
                a = mfmah(a1, b1, a);
                __builtin_amdgcn_s_setprio(0);
                #pragma unroll
                for (int reg = 0; reg < 4; ++reg) {
                    int t = t0w + quad * 4 + reg;
                    lt[st][reg] = (t >= r) ? a[reg] : NEG_BIG;
                }
            }
        }

        if (flags) {
            // per-lane chunk max (reused by both gate and slow path)
            f32x4 mc = (f32x4){NEG_BIG, NEG_BIG, NEG_BIG, NEG_BIG};
            #pragma unroll
            for (int st = 0; st < 4; ++st)
                if ((flags >> st) & 1u)
                    #pragma unroll
                    for (int reg = 0; reg < 4; ++reg)
                        mc[reg] = fmaxf(mc[reg], lt[st][reg]);
            bool need = false;
            #pragma unroll
            for (int reg = 0; reg < 4; ++reg)
                need |= mc[reg] > mrun[reg] + 8.f;
            if (__ballot(need)) {
                // slow path: cross-lane max + rescale (log2 domain)
                #pragma unroll
                for (int off = 1; off < 16; off <<= 1)
                    #pragma unroll
                    for (int reg = 0; reg < 4; ++reg)
                        mc[reg] = fmaxf(mc[reg], __shfl_xor(mc[reg], off));
                #pragma unroll
                for (int reg = 0; reg < 4; ++reg) {
                    float mnew = fmaxf(mrun[reg], mc[reg]);
                    float alpha = exp2h(mrun[reg] - mnew);
                    lsum[reg] *= alpha;
                    #pragma unroll
                    for (int dt = 0; dt < 4; ++dt) O[dt][reg] *= alpha;
                    mrun[reg] = mnew;
                }
            }
            // fast path: P = 2^(lt - mrun); masked lt underflows to exactly 0
            #pragma unroll
            for (int st = 0; st < 4; ++st) {
                if ((flags >> st) & 1u) {
                    #pragma unroll
                    for (int reg = 0; reg < 4; ++reg) {
                        float p = exp2h(lt[st][reg] - mrun[reg]);
                        lsum[reg] += p;
                        Pw[(quad * 4 + reg) * 72 + st * 16 + lm] = f2h(p);
                    }
                } else if ((flags >> (st ^ 1)) & 1u) {
                    // zeros only needed when the PV 32-set partner is active
                    #pragma unroll
                    for (int reg = 0; reg < 4; ++reg)
                        Pw[(quad * 4 + reg) * 72 + st * 16 + lm] = 0;
                }
            }

            // P @ V chunk (skip fully-masked 32-set segments), V from L2
            #pragma unroll
            for (int kc = 0; kc < 2; ++kc) {
                if (!((flags >> (2 * kc)) & 3u)) continue;
                f16x8 afr = *(const f16x8*)(Pw + lm * 72 + kc * 32 + quad * 8);
                __builtin_amdgcn_s_setprio(1);
                #pragma unroll
                for (int dt = 0; dt < 4; ++dt) {
                    size_t vo = (size_t)(dt * 16 + lm) * S_PAD + s0 + kc * 32 + quad * 8;
                    f16x8 bv = *(const f16x8*)(vb + vo);
                    O[dt] = mfmah(afr, bv, O[dt]);
                }
                __builtin_amdgcn_s_setprio(0);
            }
        }

        if (c < 7) __syncthreads();
    }

    // single cross-lane sum reduce (outside the chunk loop)
    #pragma unroll
    for (int off = 1; off < 16; off <<= 1)
        #pragma unroll
        for (int reg = 0; reg < 4; ++reg) lsum[reg] += __shfl_xor(lsum[reg], off);

    // store partials: O/l (f16) and LSE = m + log2(l) (log2 domain, f32)
    u16* Ob = Opart + ((size_t)half * 32 + bh) * T_SEQ * HS;
    float* Lb = LSEpart + ((size_t)half * 32 + bh) * T_SEQ;
    #pragma unroll
    for (int reg = 0; reg < 4; ++reg) {
        int t = t0w + quad * 4 + reg;
        float inv = lsum[reg] > 0.f ? 1.f / lsum[reg] : 0.f;
        #pragma unroll
        for (int dt = 0; dt < 4; ++dt)
            Ob[(size_t)t * HS + dt * 16 + lm] = f2h(O[dt][reg] * inv);
        if (lm == 0)
            Lb[t] = lsum[reg] > 0.f ? mrun[reg] + log2h(lsum[reg]) : NEG_BIG;
    }
}

// -------- Kernel 3b: merge two set-half partials + tail, write att16 ---------
// grid (512, 32), 256 thr: wave = one (bh,t) row, lane = dim d.
// All LSE values and the tail logit are in the log2 domain.
__global__ __launch_bounds__(256) void attn_combine(const u16* __restrict__ q16,
                                                    const u16* __restrict__ k16,
                                                    const u16* __restrict__ v16,
                                                    const u16* __restrict__ Opart,
                                                    const float* __restrict__ LSEpart,
                                                    u16* __restrict__ att16) {
    int bh = blockIdx.y;
    int wv = threadIdx.x >> 6, d = threadIdx.x & 63;
    int t = blockIdx.x * 4 + wv;
    size_t row = (size_t)bh * T_SEQ + t;

    float lse0 = LSEpart[row];
    float lse1 = LSEpart[(size_t)32 * T_SEQ + row];

    // tail: K_tail/V_tail over last (t%4)+1 positions; q16 pre-scaled (log2e)
    int len = (t & 3) + 1;
    const u16* kp = k16 + row * HS + d;
    const u16* vp = v16 + row * HS + d;
    float kt = 0.f, vt = 0.f;
    for (int j = 0; j < len; ++j) { kt += h2f(kp[-j * HS]); vt += h2f(vp[-j * HS]); }
    float tl = h2f(q16[row * HS + d]) * kt;
    #pragma unroll
    for (int off = 1; off < 64; off <<= 1) tl += __shfl_xor(tl, off);

    float mf = fmaxf(fmaxf(lse0, lse1), tl);
    float w0 = exp2h(lse0 - mf), w1 = exp2h(lse1 - mf), wt = exp2h(tl - mf);
    float inv = 1.f / (w0 + w1 + wt);
    float o0 = h2f(Opart[row * HS + d]);
    float o1 = h2f(Opart[(size_t)32 * T_SEQ * HS + row * HS + d]);
    float val = (w0 * o0 + w1 * o1 + wt * vt) * inv;

    int b_ = bh >> 4, h_ = bh & 15;
    att16[((size_t)b_ * T_SEQ + t) * C_DIM + h_ * HS + d] = f2h(val);
}

// -------- Kernel 4: out = attout @ W_proj^T, fp16 MFMA, 2-phase prefetch -----
// (round-7 version, untouched control)
__global__ __launch_bounds__(256) void gemm_proj16(const u16* __restrict__ a_,
                                                   const u16* __restrict__ w,
                                                   float* __restrict__ out) {
    __shared__ u16 As[2][128 * 32];
    __shared__ u16 Bs[2][128 * 32];
    int tid = threadIdx.x, wv = tid >> 6, lane = tid & 63;
    int lm = lane & 15, quad = lane >> 4;
    int mt = blockIdx.x >> 3, nt = blockIdx.x & 7;
    int wm = wv >> 1, wn = wv & 1;
    int m_off = wm * 64, n_off = wn * 64;

    const u16* gsrc;
    u16 *ldst0, *ldst1;
    int half = wv & 1;
    if (wv < 2) { gsrc = a_ + (size_t)(mt * 128 + half * 64) * C_DIM;
                  ldst0 = &As[0][half * 2048]; ldst1 = &As[1][half * 2048]; }
    else        { gsrc = w  + (size_t)(nt * 128 + half * 64) * C_DIM;
                  ldst0 = &Bs[0][half * 2048]; ldst1 = &Bs[1][half * 2048]; }
    int srow = lane >> 2, scol = (lane & 3) * 8;

    f32x4 acc[4][4];
    #pragma unroll
    for (int i = 0; i < 4; ++i)
        #pragma unroll
        for (int j = 0; j < 4; ++j) acc[i][j] = (f32x4){0.f, 0.f, 0.f, 0.f};

    #pragma unroll
    for (int i = 0; i < 4; ++i)
        __builtin_amdgcn_global_load_lds(
            GLB(gsrc + (size_t)(i * 16 + srow) * C_DIM + scol),
            LDS(ldst0 + i * 512), 16, 0, 0);
    __syncthreads();

    for (int k0 = 0, it = 0; k0 < C_DIM; k0 += 32, ++it) {
        const u16* Ab = (it & 1) ? &As[1][0] : &As[0][0];
        const u16* Bb = (it & 1) ? &Bs[1][0] : &Bs[0][0];
        if (k0 + 32 < C_DIM) {
            u16* nd = (it & 1) ? ldst0 : ldst1;
            #pragma unroll
            for (int i = 0; i < 4; ++i)
                __builtin_amdgcn_global_load_lds(
                    GLB(gsrc + (size_t)(i * 16 + srow) * C_DIM + k0 + 32 + scol),
                    LDS(nd + i * 512), 16, 0, 0);
        }
        f16x8 af[4], bf[4];
        #pragma unroll
        for (int i = 0; i < 4; ++i) {
            af[i] = *(const f16x8*)(Ab + (m_off + i * 16 + lm) * 32 + quad * 8);
            bf[i] = *(const f16x8*)(Bb + (n_off + i * 16 + lm) * 32 + quad * 8);
        }
        #pragma unroll
        for (int mi = 0; mi < 4; ++mi)
            #pragma unroll
            for (int ni = 0; ni < 4; ++ni)
                acc[mi][ni] = mfmah(af[mi], bf[ni], acc[mi][ni]);
        __syncthreads();
    }

    #pragma unroll
    for (int mi = 0; mi < 4; ++mi)
        #pragma unroll
        for (int ni = 0; ni < 4; ++ni) {
            int n = nt * 128 + n_off + ni * 16 + lm;
            #pragma unroll
            for (int reg = 0; reg < 4; ++reg) {
                int m = mt * 128 + m_off + mi * 16 + quad * 4 + reg;
                out[(size_t)m * C_DIM + n] = acc[mi][ni][reg];
            }
        }
}

extern "C" void kernel_launch(void* const* d_in, const int* in_sizes, int n_in,
                              void* d_out, int out_size, void* d_ws, size_t ws_size,
                              hipStream_t stream) {
    const float* x     = (const float*)d_in[0];
    const float* Wattn = (const float*)d_in[1];
    const float* Wproj = (const float*)d_in[2];
    float* out = (float*)d_out;
    char* ws = (char*)d_ws;
    // workspace layout (61.3 MB), with time-multiplexed overlays:
    //   [0, 16.78MB): x16(8MB)+wa16(6.29MB) during qkv -> Opart during attn
    u16*  Opart = (u16*)(ws + 0);            // 16,777,216 [attn partials, 2 halves]
    u16*  x16   = (u16*)(ws + 0);            //  8,388,608 (dead after gemm_qkv16)
    u16*  wa16  = (u16*)(ws + 8388608);      //  6,291,456 (dead after gemm_qkv16)
    u16*  q16   = (u16*)(ws + 16777216);     //  8,388,608 (pre-scaled, log2 dom.)
    u16*  k16   = (u16*)(ws + 25165824);     //  8,388,608
    u16*  v16   = (u16*)(ws + 33554432);     //  8,388,608
    u16*  K16   = (u16*)(ws + 41943040);     //  4,194,304
    u16*  VT16  = (u16*)(ws + 46137344);     //  4,194,304
    u16*  att16 = (u16*)(ws + 50331648);     //  8,388,608
    float* LSE  = (float*)(ws + 58720256);   //    524,288
    u16*  wp16  = (u16*)(ws + 59244544);     //  2,097,152  (end 61,341,696)

    hipLaunchKernelGGL(conv_all, dim3(8192), dim3(256), 0, stream,
                       x, Wattn, Wproj, x16, wa16, wp16);
    hipLaunchKernelGGL(gemm_qkv16, dim3(768), dim3(256), 0, stream,
                       x16, wa16, q16, k16, v16);
    hipLaunchKernelGGL(set_sums, dim3(32, 8), dim3(256), 0, stream, k16, v16, K16, VT16);
    hipLaunchKernelGGL(attn_flash16, dim3(32, 32, 2), dim3(256), 0, stream,
                       q16, K16, VT16, Opart, LSE);
    hipLaunchKernelGGL(attn_combine, dim3(512, 32), dim3(256), 0, stream,
                       q16, k16, v16, Opart, LSE, att16);
    hipLaunchKernelGGL(gemm_proj16, dim3(256), dim3(256), 0, stream, att16, wp16, out);
}

// Round 11
// 216.572 us; speedup vs baseline: 1.0489x; 1.0193x over previous
//
#include <hip/hip_runtime.h>

typedef _Float16 f16x8 __attribute__((ext_vector_type(8)));
typedef unsigned short u16x8 __attribute__((ext_vector_type(8)));
typedef float f32x4  __attribute__((ext_vector_type(4)));
typedef unsigned short u16;

#define T_SEQ 2048
#define C_DIM 1024
#define NH 16
#define HS 64
#define S_SETS 1023
#define S_PAD 1024
// q pre-scale: (1/sqrt(64)) * log2(e)  -> logits live in log2 domain,
// so softmax uses raw v_exp_f32 (2^x) with no per-element multiply.
#define SCALE2 0.18033688011112042f
#define NEG_BIG -1e30f
#define MSENT  -50000.0f   // finite sentinel: below any real logit, but
                           // exp2(NEG_BIG - MSENT) still underflows to 0

#define GLB(p) ((const __attribute__((address_space(1))) void*)(p))
#define LDS(p) ((__attribute__((address_space(3))) void*)(p))

__device__ __forceinline__ u16 f2h(float f) {
    _Float16 h = (_Float16)f;
    return __builtin_bit_cast(unsigned short, h);
}
__device__ __forceinline__ float h2f(u16 u) {
    _Float16 h = __builtin_bit_cast(_Float16, u);
    return (float)h;
}
__device__ __forceinline__ float exp2h(float x) {   // 2^x, single v_exp_f32
    float r; asm("v_exp_f32 %0, %1" : "=v"(r) : "v"(x)); return r;
}
__device__ __forceinline__ float log2h(float x) {   // log2(x)
    float r; asm("v_log_f32 %0, %1" : "=v"(r) : "v"(x)); return r;
}
__device__ __forceinline__ f32x4 mfmah(f16x8 a, f16x8 b, f32x4 c) {
    return __builtin_amdgcn_mfma_f32_16x16x32_f16(a, b, c, 0, 0, 0);
}

// -------- Kernel 0: fp32 -> fp16, all three inputs in one launch -------------
__global__ __launch_bounds__(256) void conv_all(const float* __restrict__ x,
                                                const float* __restrict__ wa,
                                                const float* __restrict__ wp,
                                                u16* __restrict__ x16,
                                                u16* __restrict__ wa16,
                                                u16* __restrict__ wp16) {
    int i = blockIdx.x * 256 + threadIdx.x;
    const float* src; u16* dst; int off;
    if (i < 1048576)              { src = x;  dst = x16;  off = i; }
    else if (i < 1048576 + 786432){ src = wa; dst = wa16; off = i - 1048576; }
    else                          { src = wp; dst = wp16; off = i - (1048576 + 786432); }
    float4 f = ((const float4*)src)[off];
    ushort4 o;
    o.x = f2h(f.x); o.y = f2h(f.y); o.z = f2h(f.z); o.w = f2h(f.w);
    ((ushort4*)dst)[off] = o;
}

// -------- Kernel 1: qkv = x @ W_attn^T, fp16 MFMA, 128x128 tile --------------
// (round-7 version: normal operand order; 16-consecutive-u16 store segments)
// 2-phase prefetch; q -> fp16 PRE-SCALED by SCALE2 (log2-domain); k,v -> fp16.
__global__ __launch_bounds__(256) void gemm_qkv16(const u16* __restrict__ x16,
                                                  const u16* __restrict__ wa16,
                                                  u16* __restrict__ q16,
                                                  u16* __restrict__ k16,
                                                  u16* __restrict__ v16) {
    __shared__ u16 As[2][128 * 32];
    __shared__ u16 Bs[2][128 * 32];
    int tid = threadIdx.x, wv = tid >> 6, lane = tid & 63;
    int lm = lane & 15, quad = lane >> 4;
    int mt = blockIdx.x / 24, nt = blockIdx.x % 24;
    int wm = wv >> 1, wn = wv & 1;
    int m_off = wm * 64, n_off = wn * 64;

    const u16* gsrc;
    u16 *ldst0, *ldst1;
    int half = wv & 1;
    if (wv < 2) { gsrc = x16  + (size_t)(mt * 128 + half * 64) * C_DIM;
                  ldst0 = &As[0][half * 2048]; ldst1 = &As[1][half * 2048]; }
    else        { gsrc = wa16 + (size_t)(nt * 128 + half * 64) * C_DIM;
                  ldst0 = &Bs[0][half * 2048]; ldst1 = &Bs[1][half * 2048]; }
    int srow = lane >> 2, scol = (lane & 3) * 8;

    f32x4 acc[4][4];
    #pragma unroll
    for (int i = 0; i < 4; ++i)
        #pragma unroll
        for (int j = 0; j < 4; ++j) acc[i][j] = (f32x4){0.f, 0.f, 0.f, 0.f};

    #pragma unroll
    for (int i = 0; i < 4; ++i)
        __builtin_amdgcn_global_load_lds(
            GLB(gsrc + (size_t)(i * 16 + srow) * C_DIM + scol),
            LDS(ldst0 + i * 512), 16, 0, 0);
    __syncthreads();

    for (int k0 = 0, it = 0; k0 < C_DIM; k0 += 32, ++it) {
        const u16* Ab = (it & 1) ? &As[1][0] : &As[0][0];
        const u16* Bb = (it & 1) ? &Bs[1][0] : &Bs[0][0];
        if (k0 + 32 < C_DIM) {
            u16* nd = (it & 1) ? ldst0 : ldst1;
            #pragma unroll
            for (int i = 0; i < 4; ++i)
                __builtin_amdgcn_global_load_lds(
                    GLB(gsrc + (size_t)(i * 16 + srow) * C_DIM + k0 + 32 + scol),
                    LDS(nd + i * 512), 16, 0, 0);
        }
        f16x8 af[4], bf[4];
        #pragma unroll
        for (int i = 0; i < 4; ++i) {
            af[i] = *(const f16x8*)(Ab + (m_off + i * 16 + lm) * 32 + quad * 8);
            bf[i] = *(const f16x8*)(Bb + (n_off + i * 16 + lm) * 32 + quad * 8);
        }
        #pragma unroll
        for (int mi = 0; mi < 4; ++mi)
            #pragma unroll
            for (int ni = 0; ni < 4; ++ni)
                acc[mi][ni] = mfmah(af[mi], bf[ni], acc[mi][ni]);
        __syncthreads();
    }

    #pragma unroll
    for (int mi = 0; mi < 4; ++mi)
        #pragma unroll
        for (int ni = 0; ni < 4; ++ni) {
            int n = nt * 128 + n_off + ni * 16 + lm;
            int which = n >> 10, h = (n >> 6) & 15, d = n & 63;
            #pragma unroll
            for (int reg = 0; reg < 4; ++reg) {
                int m = mt * 128 + m_off + mi * 16 + quad * 4 + reg;
                int b_ = m >> 11, t = m & 2047;
                size_t oi = (((size_t)(b_ * NH + h)) * T_SEQ + t) * HS + d;
                float val = acc[mi][ni][reg];
                if (which == 0)      q16[oi] = f2h(val * SCALE2);
                else if (which == 1) k16[oi] = f2h(val);
                else                 v16[oi] = f2h(val);
            }
        }
}

// -------- Kernel 2: hierarchical set sums (fp16 in) -> fp16 outputs ----------
// Level-0 loads vectorized: per task (sg, h) 4x u16x8 (16B) loads, vector
// K16 store; f32 tree in LDS unchanged.
__global__ __launch_bounds__(256) void set_sums(const u16* __restrict__ k16,
                                                const u16* __restrict__ v16,
                                                u16* __restrict__ K16,
                                                u16* __restrict__ VT16) {
    int bh  = blockIdx.x;
    int src = blockIdx.y >> 2;
    int dc  = blockIdx.y & 3;
    int tid = threadIdx.x;
    __shared__ float lv0[512 * 16];
    __shared__ float lv1[256 * 16];
    const u16* sp = src ? v16 : k16;
    u16* op = src ? VT16 : K16;
    int dbase = dc * 16;
    // zero the padded set row/col 1023 (staged unmasked by the attn kernel)
    if (tid < 16) {
        int d = dbase + tid;
        size_t o = src ? ((size_t)bh * HS + d) * S_PAD + 1023
                       : ((size_t)bh * S_PAD + 1023) * HS + d;
        op[o] = 0;
    }
    // level 0: 1024 tasks (sg in [0,512), h in {0,1}), 4 per thread
    for (int task = tid; task < 1024; task += 256) {
        int sg = task >> 1, h = task & 1;
        int d0 = dbase + h * 8;
        const u16* p = sp + ((size_t)bh * T_SEQ + sg * 4) * HS + d0;
        u16x8 r0 = *(const u16x8*)(p);
        u16x8 r1 = *(const u16x8*)(p + HS);
        u16x8 r2 = *(const u16x8*)(p + 2 * HS);
        u16x8 r3 = *(const u16x8*)(p + 3 * HS);
        float s[8];
        #pragma unroll
        for (int e = 0; e < 8; ++e) {
            s[e] = h2f(r0[e]) + h2f(r1[e]) + h2f(r2[e]) + h2f(r3[e]);
            lv0[sg * 16 + h * 8 + e] = s[e];
        }
        if (src) {
            #pragma unroll
            for (int e = 0; e < 8; ++e)
                op[((size_t)bh * HS + d0 + e) * S_PAD + sg] = f2h(s[e]);
        } else {
            u16x8 ov;
            #pragma unroll
            for (int e = 0; e < 8; ++e) ov[e] = f2h(s[e]);
            *(u16x8*)(op + ((size_t)bh * S_PAD + sg) * HS + d0) = ov;
        }
    }
    __syncthreads();
    int nsets = 256, offset = 512, lvl = 1;
    while (nsets >= 1) {
        float* sbuf = (lvl & 1) ? lv0 : lv1;
        float* dbuf = (lvl & 1) ? lv1 : lv0;
        for (int idx = tid; idx < nsets * 16; idx += 256) {
            int i = idx >> 4, dd = idx & 15, d = dbase + dd;
            float s = sbuf[(2 * i) * 16 + dd] + sbuf[(2 * i + 1) * 16 + dd];
            dbuf[i * 16 + dd] = s;
            int so = offset + i;
            size_t o = src ? ((size_t)bh * HS + d) * S_PAD + so
                           : ((size_t)bh * S_PAD + so) * HS + d;
            op[o] = f2h(s);
        }
        __syncthreads();
        offset += nsets; nsets >>= 1; lvl++;
    }
}

// -------- Kernel 3: flash attention over set-halves ---------------------------
// (round-7 version: no setprio — null for barrier-synced lockstep waves)
// grid (32, 32, 2): x = bh (XCD-pinned), y = query-group pair, z = set-half.
// log2-domain softmax; deferred-max; single epilogue reduce.
__global__ __launch_bounds__(256) void attn_flash16(const u16* __restrict__ q16,
                                                    const u16* __restrict__ K16,
                                                    const u16* __restrict__ VT16,
                                                    u16* __restrict__ Opart,
                                                    float* __restrict__ LSEpart) {
    int bh = blockIdx.x;
    int half = blockIdx.z;
    int tid = threadIdx.x, wv = tid >> 6, lane = tid & 63;
    int lm = lane & 15, quad = lane >> 4;
    int tgrp = (wv < 2) ? (32 * blockIdx.y) : (2016 - 32 * blockIdx.y);
    int t0w = tgrp + (wv & 1) * 16;
    int twmax = t0w + 15;
    int sbase = half * 512;

    __shared__ u16 Ks[2][64 * 64];    // dbuf K chunk fp16, XOR-swizzled (16 KB)
    __shared__ u16 Pbuf[4][16 * 72];  // per-wave P fp16 (9.2 KB)
    __shared__ u16 rtab[512];         // mask boundary r(s) for this half (1 KB)

    const u16* qg = q16 + ((size_t)bh * T_SEQ + t0w + lm) * HS;
    f16x8 a0 = *(const f16x8*)(qg + quad * 8);
    f16x8 a1 = *(const f16x8*)(qg + 32 + quad * 8);

    // build r-table once (2 entries/thread); covered by the staging barrier
    #pragma unroll
    for (int i = tid; i < 512; i += 256) {
        int s = sbase + i;
        unsigned rv = 0xFFFFu;
        if (s < S_SETS) {
            int e = S_SETS - s;
            int l = __clz(e) - 22;          // level: L = 4<<l
            int i0 = s - (1024 - (1024 >> l));
            rv = (unsigned)((i0 + 1) * (4 << l) - 1);
        }
        rtab[i] = (u16)rv;
    }

    f32x4 O[4];
    #pragma unroll
    for (int i = 0; i < 4; ++i) O[i] = (f32x4){0.f, 0.f, 0.f, 0.f};
    f32x4 mrun = (f32x4){MSENT, MSENT, MSENT, MSENT};
    f32x4 lsum = (f32x4){0.f, 0.f, 0.f, 0.f};

    u16* Pw = &Pbuf[wv][0];
    const u16* vb  = VT16 + (size_t)bh * HS * S_PAD;
    const u16* kbh = K16  + ((size_t)bh * S_PAD + sbase) * HS;

    // gload_lds staging: wave wv covers rows [wv*16, wv*16+16) per chunk.
    // Global source pre-swizzled; LINEAR LDS dest.
    int l8 = lane >> 3;
    int lg = (lane & 7) ^ l8;
    const u16* gsw = kbh + (size_t)(wv * 16 + l8) * HS + lg * 8;

    // prologue: stage chunk 0 into buf 0
    __builtin_amdgcn_global_load_lds(GLB(gsw),       LDS(&Ks[0][wv * 1024]),       16, 0, 0);
    __builtin_amdgcn_global_load_lds(GLB(gsw + 512), LDS(&Ks[0][wv * 1024 + 512]), 16, 0, 0);
    __syncthreads();

    for (int c = 0; c < 8; ++c) {
        int cur = c & 1;
        int s0 = sbase + c * 64;
        const u16* Ksb = &Ks[cur][0];

        // issue next chunk's DMA into the alternate buffer
        if (c < 7) {
            const u16* gn = gsw + (size_t)(c + 1) * 4096;
            __builtin_amdgcn_global_load_lds(GLB(gn),       LDS(&Ks[cur ^ 1][wv * 1024]),       16, 0, 0);
            __builtin_amdgcn_global_load_lds(GLB(gn + 512), LDS(&Ks[cur ^ 1][wv * 1024 + 512]), 16, 0, 0);
        }

        // mask boundaries for this chunk's 4 s-tiles (from LDS table)
        int r4[4];
        #pragma unroll
        for (int st = 0; st < 4; ++st) r4[st] = rtab[c * 64 + st * 16 + lm];

        // QK^T: 4 s-tiles, masked, wave-uniform skip
        unsigned flags = 0;
        f32x4 lt[4];
        #pragma unroll
        for (int st = 0; st < 4; ++st) {
            int r = r4[st];
            unsigned long long bal = __ballot(r <= twmax);
            if (bal) {
                flags |= 1u << st;
                int sl = st * 16 + lm, sx = sl & 7;
                f16x8 b0 = *(const f16x8*)(Ksb + sl * 64 + ((quad ^ sx) << 3));
                f16x8 b1 = *(const f16x8*)(Ksb + sl * 64 + (((4 + quad) ^ sx) << 3));
                f32x4 a = (f32x4){0.f, 0.f, 0.f, 0.f};
                a = mfmah(a0, b0, a);
                a = mfmah(a1, b1, a);
                #pragma unroll
                for (int reg = 0; reg < 4; ++reg) {
                    int t = t0w + quad * 4 + reg;
                    lt[st][reg] = (t >= r) ? a[reg] : NEG_BIG;
                }
            }
        }

        if (flags) {
            // per-lane chunk max (reused by both gate and slow path)
            f32x4 mc = (f32x4){NEG_BIG, NEG_BIG, NEG_BIG, NEG_BIG};
            #pragma unroll
            for (int st = 0; st < 4; ++st)
                if ((flags >> st) & 1u)
                    #pragma unroll
                    for (int reg = 0; reg < 4; ++reg)
                        mc[reg] = fmaxf(mc[reg], lt[st][reg]);
            bool need = false;
            #pragma unroll
            for (int reg = 0; reg < 4; ++reg)
                need |= mc[reg] > mrun[reg] + 8.f;
            if (__ballot(need)) {
                // slow path: cross-lane max + rescale (log2 domain)
                #pragma unroll
                for (int off = 1; off < 16; off <<= 1)
                    #pragma unroll
                    for (int reg = 0; reg < 4; ++reg)
                        mc[reg] = fmaxf(mc[reg], __shfl_xor(mc[reg], off));
                #pragma unroll
                for (int reg = 0; reg < 4; ++reg) {
                    float mnew = fmaxf(mrun[reg], mc[reg]);
                    float alpha = exp2h(mrun[reg] - mnew);
                    lsum[reg] *= alpha;
                    #pragma unroll
                    for (int dt = 0; dt < 4; ++dt) O[dt][reg] *= alpha;
                    mrun[reg] = mnew;
                }
            }
            // fast path: P = 2^(lt - mrun); masked lt underflows to exactly 0
            #pragma unroll
            for (int st = 0; st < 4; ++st) {
                if ((flags >> st) & 1u) {
                    #pragma unroll
                    for (int reg = 0; reg < 4; ++reg) {
                        float p = exp2h(lt[st][reg] - mrun[reg]);
                        lsum[reg] += p;
                        Pw[(quad * 4 + reg) * 72 + st * 16 + lm] = f2h(p);
                    }
                } else if ((flags >> (st ^ 1)) & 1u) {
                    // zeros only needed when the PV 32-set partner is active
                    #pragma unroll
                    for (int reg = 0; reg < 4; ++reg)
                        Pw[(quad * 4 + reg) * 72 + st * 16 + lm] = 0;
                }
            }

            // P @ V chunk (skip fully-masked 32-set segments), V from L2
            #pragma unroll
            for (int kc = 0; kc < 2; ++kc) {
                if (!((flags >> (2 * kc)) & 3u)) continue;
                f16x8 afr = *(const f16x8*)(Pw + lm * 72 + kc * 32 + quad * 8);
                #pragma unroll
                for (int dt = 0; dt < 4; ++dt) {
                    size_t vo = (size_t)(dt * 16 + lm) * S_PAD + s0 + kc * 32 + quad * 8;
                    f16x8 bv = *(const f16x8*)(vb + vo);
                    O[dt] = mfmah(afr, bv, O[dt]);
                }
            }
        }

        if (c < 7) __syncthreads();
    }

    // single cross-lane sum reduce (outside the chunk loop)
    #pragma unroll
    for (int off = 1; off < 16; off <<= 1)
        #pragma unroll
        for (int reg = 0; reg < 4; ++reg) lsum[reg] += __shfl_xor(lsum[reg], off);

    // store partials: O/l (f16) and LSE = m + log2(l) (log2 domain, f32)
    u16* Ob = Opart + ((size_t)half * 32 + bh) * T_SEQ * HS;
    float* Lb = LSEpart + ((size_t)half * 32 + bh) * T_SEQ;
    #pragma unroll
    for (int reg = 0; reg < 4; ++reg) {
        int t = t0w + quad * 4 + reg;
        float inv = lsum[reg] > 0.f ? 1.f / lsum[reg] : 0.f;
        #pragma unroll
        for (int dt = 0; dt < 4; ++dt)
            Ob[(size_t)t * HS + dt * 16 + lm] = f2h(O[dt][reg] * inv);
        if (lm == 0)
            Lb[t] = lsum[reg] > 0.f ? mrun[reg] + log2h(lsum[reg]) : NEG_BIG;
    }
}

// -------- Kernel 3b: merge two set-half partials + tail, write att16 ---------
// grid (512, 32), 256 thr: wave = one (bh,t) row, lane = dim d.
// All LSE values and the tail logit are in the log2 domain.
__global__ __launch_bounds__(256) void attn_combine(const u16* __restrict__ q16,
                                                    const u16* __restrict__ k16,
                                                    const u16* __restrict__ v16,
                                                    const u16* __restrict__ Opart,
                                                    const float* __restrict__ LSEpart,
                                                    u16* __restrict__ att16) {
    int bh = blockIdx.y;
    int wv = threadIdx.x >> 6, d = threadIdx.x & 63;
    int t = blockIdx.x * 4 + wv;
    size_t row = (size_t)bh * T_SEQ + t;

    float lse0 = LSEpart[row];
    float lse1 = LSEpart[(size_t)32 * T_SEQ + row];

    // tail: K_tail/V_tail over last (t%4)+1 positions; q16 pre-scaled (log2e)
    int len = (t & 3) + 1;
    const u16* kp = k16 + row * HS + d;
    const u16* vp = v16 + row * HS + d;
    float kt = 0.f, vt = 0.f;
    for (int j = 0; j < len; ++j) { kt += h2f(kp[-j * HS]); vt += h2f(vp[-j * HS]); }
    float tl = h2f(q16[row * HS + d]) * kt;
    #pragma unroll
    for (int off = 1; off < 64; off <<= 1) tl += __shfl_xor(tl, off);

    float mf = fmaxf(fmaxf(lse0, lse1), tl);
    float w0 = exp2h(lse0 - mf), w1 = exp2h(lse1 - mf), wt = exp2h(tl - mf);
    float inv = 1.f / (w0 + w1 + wt);
    float o0 = h2f(Opart[row * HS + d]);
    float o1 = h2f(Opart[(size_t)32 * T_SEQ * HS + row * HS + d]);
    float val = (w0 * o0 + w1 * o1 + wt * vt) * inv;

    int b_ = bh >> 4, h_ = bh & 15;
    att16[((size_t)b_ * T_SEQ + t) * C_DIM + h_ * HS + d] = f2h(val);
}

// -------- Kernel 4: out = attout @ W_proj^T, fp16 MFMA, 64x128 M-split -------
// grid 512 = 64 mt x 8 nt (mt = id&63 -> xcd = mt%8: each XCD re-reads a 1 MB
// A-slice (L2-hit across nt) and streams W (2 MB, L2-resident)).
// 2 blocks/CU (8 waves/CU) vs prior 1. 2-phase prefetch; wave = 32x64 out.
__global__ __launch_bounds__(256) void gemm_proj16(const u16* __restrict__ a_,
                                                   const u16* __restrict__ w,
                                                   float* __restrict__ out) {
    __shared__ u16 As[2][64 * 32];     // 8 KB
    __shared__ u16 Bs[2][128 * 32];    // 16 KB
    int tid = threadIdx.x, wv = tid >> 6, lane = tid & 63;
    int lm = lane & 15, quad = lane >> 4;
    int mt = blockIdx.x & 63, nt = blockIdx.x >> 6;
    int wm = wv >> 1, wn = wv & 1;
    int m_off = wm * 32, n_off = wn * 64;

    // cooperative staging: 256 threads x 3 rounds (A 64 rows, B 128 rows)
    int srow = tid >> 2, scol = (tid & 3) * 8;
    const u16* ga  = a_ + (size_t)(mt * 64 + srow) * C_DIM + scol;
    const u16* gb0 = w  + (size_t)(nt * 128 + srow) * C_DIM + scol;
    const u16* gb1 = w  + (size_t)(nt * 128 + 64 + srow) * C_DIM + scol;
    int aoff = srow * 32 + scol, boff1 = (64 + srow) * 32 + scol;

    f32x4 acc[2][4];
    #pragma unroll
    for (int i = 0; i < 2; ++i)
        #pragma unroll
        for (int j = 0; j < 4; ++j) acc[i][j] = (f32x4){0.f, 0.f, 0.f, 0.f};

    // prologue: stage k0=0 into buffer 0
    __builtin_amdgcn_global_load_lds(GLB(ga),  LDS(&As[0][aoff]),  16, 0, 0);
    __builtin_amdgcn_global_load_lds(GLB(gb0), LDS(&Bs[0][aoff]),  16, 0, 0);
    __builtin_amdgcn_global_load_lds(GLB(gb1), LDS(&Bs[0][boff1]), 16, 0, 0);
    __syncthreads();

    for (int k0 = 0, it = 0; k0 < C_DIM; k0 += 32, ++it) {
        const u16* Ab = &As[it & 1][0];
        const u16* Bb = &Bs[it & 1][0];
        if (k0 + 32 < C_DIM) {
            int nb = (it & 1) ^ 1;
            __builtin_amdgcn_global_load_lds(GLB(ga  + k0 + 32), LDS(&As[nb][aoff]),  16, 0, 0);
            __builtin_amdgcn_global_load_lds(GLB(gb0 + k0 + 32), LDS(&Bs[nb][aoff]),  16, 0, 0);
            __builtin_amdgcn_global_load_lds(GLB(gb1 + k0 + 32), LDS(&Bs[nb][boff1]), 16, 0, 0);
        }
        f16x8 af[2], bf[4];
        #pragma unroll
        for (int i = 0; i < 2; ++i)
            af[i] = *(const f16x8*)(Ab + (m_off + i * 16 + lm) * 32 + quad * 8);
        #pragma unroll
        for (int i = 0; i < 4; ++i)
            bf[i] = *(const f16x8*)(Bb + (n_off + i * 16 + lm) * 32 + quad * 8);
        #pragma unroll
        for (int mi = 0; mi < 2; ++mi)
            #pragma unroll
            for (int ni = 0; ni < 4; ++ni)
                acc[mi][ni] = mfmah(af[mi], bf[ni], acc[mi][ni]);
        __syncthreads();
    }

    #pragma unroll
    for (int mi = 0; mi < 2; ++mi)
        #pragma unroll
        for (int ni = 0; ni < 4; ++ni) {
            int n = nt * 128 + n_off + ni * 16 + lm;
            #pragma unroll
            for (int reg = 0; reg < 4; ++reg) {
                int m = mt * 64 + m_off + mi * 16 + quad * 4 + reg;
                out[(size_t)m * C_DIM + n] = acc[mi][ni][reg];
            }
        }
}

extern "C" void kernel_launch(void* const* d_in, const int* in_sizes, int n_in,
                              void* d_out, int out_size, void* d_ws, size_t ws_size,
                              hipStream_t stream) {
    const float* x     = (const float*)d_in[0];
    const float* Wattn = (const float*)d_in[1];
    const float* Wproj = (const float*)d_in[2];
    float* out = (float*)d_out;
    char* ws = (char*)d_ws;
    // workspace layout (61.3 MB), with time-multiplexed overlays:
    //   [0, 16.78MB): x16(8MB)+wa16(6.29MB) during qkv -> Opart during attn
    u16*  Opart = (u16*)(ws + 0);            // 16,777,216 [attn partials, 2 halves]
    u16*  x16   = (u16*)(ws + 0);            //  8,388,608 (dead after gemm_qkv16)
    u16*  wa16  = (u16*)(ws + 8388608);      //  6,291,456 (dead after gemm_qkv16)
    u16*  q16   = (u16*)(ws + 16777216);     //  8,388,608 (pre-scaled, log2 dom.)
    u16*  k16   = (u16*)(ws + 25165824);     //  8,388,608
    u16*  v16   = (u16*)(ws + 33554432);     //  8,388,608
    u16*  K16   = (u16*)(ws + 41943040);     //  4,194,304
    u16*  VT16  = (u16*)(ws + 46137344);     //  4,194,304
    u16*  att16 = (u16*)(ws + 50331648);     //  8,388,608
    float* LSE  = (float*)(ws + 58720256);   //    524,288
    u16*  wp16  = (u16*)(ws + 59244544);     //  2,097,152  (end 61,341,696)

    hipLaunchKernelGGL(conv_all, dim3(8192), dim3(256), 0, stream,
                       x, Wattn, Wproj, x16, wa16, wp16);
    hipLaunchKernelGGL(gemm_qkv16, dim3(768), dim3(256), 0, stream,
                       x16, wa16, q16, k16, v16);
    hipLaunchKernelGGL(set_sums, dim3(32, 8), dim3(256), 0, stream, k16, v16, K16, VT16);
    hipLaunchKernelGGL(attn_flash16, dim3(32, 32, 2), dim3(256), 0, stream,
                       q16, K16, VT16, Opart, LSE);
    hipLaunchKernelGGL(attn_combine, dim3(512, 32), dim3(256), 0, stream,
                       q16, k16, v16, Opart, LSE, att16);
    hipLaunchKernelGGL(gemm_proj16, dim3(512), dim3(256), 0, stream, att16, wp16, out);
}

// Round 12
// 215.386 us; speedup vs baseline: 1.0546x; 1.0055x over previous
//
#include <hip/hip_runtime.h>

typedef _Float16 f16x8 __attribute__((ext_vector_type(8)));
typedef unsigned short u16x8 __attribute__((ext_vector_type(8)));
typedef float f32x4  __attribute__((ext_vector_type(4)));
typedef unsigned short u16;

#define T_SEQ 2048
#define C_DIM 1024
#define NH 16
#define HS 64
#define S_SETS 1023
#define S_PAD 1024
// q pre-scale: (1/sqrt(64)) * log2(e)  -> logits live in log2 domain,
// so softmax uses raw v_exp_f32 (2^x) with no per-element multiply.
#define SCALE2 0.18033688011112042f
#define NEG_BIG -1e30f
#define MSENT  -50000.0f   // finite sentinel: below any real logit, but
                           // exp2(NEG_BIG - MSENT) still underflows to 0

#define GLB(p) ((const __attribute__((address_space(1))) void*)(p))
#define LDS(p) ((__attribute__((address_space(3))) void*)(p))

__device__ __forceinline__ u16 f2h(float f) {
    _Float16 h = (_Float16)f;
    return __builtin_bit_cast(unsigned short, h);
}
__device__ __forceinline__ float h2f(u16 u) {
    _Float16 h = __builtin_bit_cast(_Float16, u);
    return (float)h;
}
__device__ __forceinline__ float exp2h(float x) {   // 2^x, single v_exp_f32
    float r; asm("v_exp_f32 %0, %1" : "=v"(r) : "v"(x)); return r;
}
__device__ __forceinline__ float log2h(float x) {   // log2(x)
    float r; asm("v_log_f32 %0, %1" : "=v"(r) : "v"(x)); return r;
}
__device__ __forceinline__ f32x4 mfmah(f16x8 a, f16x8 b, f32x4 c) {
    return __builtin_amdgcn_mfma_f32_16x16x32_f16(a, b, c, 0, 0, 0);
}

// -------- Kernel 0: fp32 -> fp16, all three inputs in one launch -------------
__global__ __launch_bounds__(256) void conv_all(const float* __restrict__ x,
                                                const float* __restrict__ wa,
                                                const float* __restrict__ wp,
                                                u16* __restrict__ x16,
                                                u16* __restrict__ wa16,
                                                u16* __restrict__ wp16) {
    int i = blockIdx.x * 256 + threadIdx.x;
    const float* src; u16* dst; int off;
    if (i < 1048576)              { src = x;  dst = x16;  off = i; }
    else if (i < 1048576 + 786432){ src = wa; dst = wa16; off = i - 1048576; }
    else                          { src = wp; dst = wp16; off = i - (1048576 + 786432); }
    float4 f = ((const float4*)src)[off];
    ushort4 o;
    o.x = f2h(f.x); o.y = f2h(f.y); o.z = f2h(f.z); o.w = f2h(f.w);
    ((ushort4*)dst)[off] = o;
}

// -------- Kernel 1: qkv = x @ W_attn^T, fp16 MFMA, 128x128 tile --------------
// (round-7 version: normal operand order; 16-consecutive-u16 store segments)
// 2-phase prefetch; q -> fp16 PRE-SCALED by SCALE2 (log2-domain); k,v -> fp16.
__global__ __launch_bounds__(256) void gemm_qkv16(const u16* __restrict__ x16,
                                                  const u16* __restrict__ wa16,
                                                  u16* __restrict__ q16,
                                                  u16* __restrict__ k16,
                                                  u16* __restrict__ v16) {
    __shared__ u16 As[2][128 * 32];
    __shared__ u16 Bs[2][128 * 32];
    int tid = threadIdx.x, wv = tid >> 6, lane = tid & 63;
    int lm = lane & 15, quad = lane >> 4;
    int mt = blockIdx.x / 24, nt = blockIdx.x % 24;
    int wm = wv >> 1, wn = wv & 1;
    int m_off = wm * 64, n_off = wn * 64;

    const u16* gsrc;
    u16 *ldst0, *ldst1;
    int half = wv & 1;
    if (wv < 2) { gsrc = x16  + (size_t)(mt * 128 + half * 64) * C_DIM;
                  ldst0 = &As[0][half * 2048]; ldst1 = &As[1][half * 2048]; }
    else        { gsrc = wa16 + (size_t)(nt * 128 + half * 64) * C_DIM;
                  ldst0 = &Bs[0][half * 2048]; ldst1 = &Bs[1][half * 2048]; }
    int srow = lane >> 2, scol = (lane & 3) * 8;

    f32x4 acc[4][4];
    #pragma unroll
    for (int i = 0; i < 4; ++i)
        #pragma unroll
        for (int j = 0; j < 4; ++j) acc[i][j] = (f32x4){0.f, 0.f, 0.f, 0.f};

    #pragma unroll
    for (int i = 0; i < 4; ++i)
        __builtin_amdgcn_global_load_lds(
            GLB(gsrc + (size_t)(i * 16 + srow) * C_DIM + scol),
            LDS(ldst0 + i * 512), 16, 0, 0);
    __syncthreads();

    for (int k0 = 0, it = 0; k0 < C_DIM; k0 += 32, ++it) {
        const u16* Ab = (it & 1) ? &As[1][0] : &As[0][0];
        const u16* Bb = (it & 1) ? &Bs[1][0] : &Bs[0][0];
        if (k0 + 32 < C_DIM) {
            u16* nd = (it & 1) ? ldst0 : ldst1;
            #pragma unroll
            for (int i = 0; i < 4; ++i)
                __builtin_amdgcn_global_load_lds(
                    GLB(gsrc + (size_t)(i * 16 + srow) * C_DIM + k0 + 32 + scol),
                    LDS(nd + i * 512), 16, 0, 0);
        }
        f16x8 af[4], bf[4];
        #pragma unroll
        for (int i = 0; i < 4; ++i) {
            af[i] = *(const f16x8*)(Ab + (m_off + i * 16 + lm) * 32 + quad * 8);
            bf[i] = *(const f16x8*)(Bb + (n_off + i * 16 + lm) * 32 + quad * 8);
        }
        #pragma unroll
        for (int mi = 0; mi < 4; ++mi)
            #pragma unroll
            for (int ni = 0; ni < 4; ++ni)
                acc[mi][ni] = mfmah(af[mi], bf[ni], acc[mi][ni]);
        __syncthreads();
    }

    #pragma unroll
    for (int mi = 0; mi < 4; ++mi)
        #pragma unroll
        for (int ni = 0; ni < 4; ++ni) {
            int n = nt * 128 + n_off + ni * 16 + lm;
            int which = n >> 10, h = (n >> 6) & 15, d = n & 63;
            #pragma unroll
            for (int reg = 0; reg < 4; ++reg) {
                int m = mt * 128 + m_off + mi * 16 + quad * 4 + reg;
                int b_ = m >> 11, t = m & 2047;
                size_t oi = (((size_t)(b_ * NH + h)) * T_SEQ + t) * HS + d;
                float val = acc[mi][ni][reg];
                if (which == 0)      q16[oi] = f2h(val * SCALE2);
                else if (which == 1) k16[oi] = f2h(val);
                else                 v16[oi] = f2h(val);
            }
        }
}

// -------- Kernel 2: hierarchical set sums (fp16 in) -> fp16 outputs ----------
// Level-0 loads vectorized: per task (sg, h) 4x u16x8 (16B) loads, vector
// K16 store; f32 tree in LDS unchanged.
__global__ __launch_bounds__(256) void set_sums(const u16* __restrict__ k16,
                                                const u16* __restrict__ v16,
                                                u16* __restrict__ K16,
                                                u16* __restrict__ VT16) {
    int bh  = blockIdx.x;
    int src = blockIdx.y >> 2;
    int dc  = blockIdx.y & 3;
    int tid = threadIdx.x;
    __shared__ float lv0[512 * 16];
    __shared__ float lv1[256 * 16];
    const u16* sp = src ? v16 : k16;
    u16* op = src ? VT16 : K16;
    int dbase = dc * 16;
    // zero the padded set row/col 1023 (staged unmasked by the attn kernel)
    if (tid < 16) {
        int d = dbase + tid;
        size_t o = src ? ((size_t)bh * HS + d) * S_PAD + 1023
                       : ((size_t)bh * S_PAD + 1023) * HS + d;
        op[o] = 0;
    }
    // level 0: 1024 tasks (sg in [0,512), h in {0,1}), 4 per thread
    for (int task = tid; task < 1024; task += 256) {
        int sg = task >> 1, h = task & 1;
        int d0 = dbase + h * 8;
        const u16* p = sp + ((size_t)bh * T_SEQ + sg * 4) * HS + d0;
        u16x8 r0 = *(const u16x8*)(p);
        u16x8 r1 = *(const u16x8*)(p + HS);
        u16x8 r2 = *(const u16x8*)(p + 2 * HS);
        u16x8 r3 = *(const u16x8*)(p + 3 * HS);
        float s[8];
        #pragma unroll
        for (int e = 0; e < 8; ++e) {
            s[e] = h2f(r0[e]) + h2f(r1[e]) + h2f(r2[e]) + h2f(r3[e]);
            lv0[sg * 16 + h * 8 + e] = s[e];
        }
        if (src) {
            #pragma unroll
            for (int e = 0; e < 8; ++e)
                op[((size_t)bh * HS + d0 + e) * S_PAD + sg] = f2h(s[e]);
        } else {
            u16x8 ov;
            #pragma unroll
            for (int e = 0; e < 8; ++e) ov[e] = f2h(s[e]);
            *(u16x8*)(op + ((size_t)bh * S_PAD + sg) * HS + d0) = ov;
        }
    }
    __syncthreads();
    int nsets = 256, offset = 512, lvl = 1;
    while (nsets >= 1) {
        float* sbuf = (lvl & 1) ? lv0 : lv1;
        float* dbuf = (lvl & 1) ? lv1 : lv0;
        for (int idx = tid; idx < nsets * 16; idx += 256) {
            int i = idx >> 4, dd = idx & 15, d = dbase + dd;
            float s = sbuf[(2 * i) * 16 + dd] + sbuf[(2 * i + 1) * 16 + dd];
            dbuf[i * 16 + dd] = s;
            int so = offset + i;
            size_t o = src ? ((size_t)bh * HS + d) * S_PAD + so
                           : ((size_t)bh * S_PAD + so) * HS + d;
            op[o] = f2h(s);
        }
        __syncthreads();
        offset += nsets; nsets >>= 1; lvl++;
    }
}

// -------- Kernel 3: flash attention over set-halves ---------------------------
// grid (32, 32, 2): x = bh (XCD-pinned), y = query-group pair, z = set-half.
// SINGLE-buffered Ks (8 KB): LDS 26.6 -> 18.4 KB so all 8 blocks/CU are
// co-resident (32 waves/CU) -- inter-block TLP replaces the dbuf's overlap.
// Per chunk: stage -> barrier -> compute -> barrier.
// log2-domain softmax; deferred-max; single epilogue reduce.
__global__ __launch_bounds__(256) void attn_flash16(const u16* __restrict__ q16,
                                                    const u16* __restrict__ K16,
                                                    const u16* __restrict__ VT16,
                                                    u16* __restrict__ Opart,
                                                    float* __restrict__ LSEpart) {
    int bh = blockIdx.x;
    int half = blockIdx.z;
    int tid = threadIdx.x, wv = tid >> 6, lane = tid & 63;
    int lm = lane & 15, quad = lane >> 4;
    int tgrp = (wv < 2) ? (32 * blockIdx.y) : (2016 - 32 * blockIdx.y);
    int t0w = tgrp + (wv & 1) * 16;
    int twmax = t0w + 15;
    int sbase = half * 512;

    __shared__ u16 Ks[64 * 64];       // K chunk fp16, XOR-swizzled (8 KB)
    __shared__ u16 Pbuf[4][16 * 72];  // per-wave P fp16 (9.2 KB)
    __shared__ u16 rtab[512];         // mask boundary r(s) for this half (1 KB)

    const u16* qg = q16 + ((size_t)bh * T_SEQ + t0w + lm) * HS;
    f16x8 a0 = *(const f16x8*)(qg + quad * 8);
    f16x8 a1 = *(const f16x8*)(qg + 32 + quad * 8);

    // build r-table once (2 entries/thread); covered by the staging barrier
    #pragma unroll
    for (int i = tid; i < 512; i += 256) {
        int s = sbase + i;
        unsigned rv = 0xFFFFu;
        if (s < S_SETS) {
            int e = S_SETS - s;
            int l = __clz(e) - 22;          // level: L = 4<<l
            int i0 = s - (1024 - (1024 >> l));
            rv = (unsigned)((i0 + 1) * (4 << l) - 1);
        }
        rtab[i] = (u16)rv;
    }

    f32x4 O[4];
    #pragma unroll
    for (int i = 0; i < 4; ++i) O[i] = (f32x4){0.f, 0.f, 0.f, 0.f};
    f32x4 mrun = (f32x4){MSENT, MSENT, MSENT, MSENT};
    f32x4 lsum = (f32x4){0.f, 0.f, 0.f, 0.f};

    u16* Pw = &Pbuf[wv][0];
    const u16* vb  = VT16 + (size_t)bh * HS * S_PAD;
    const u16* kbh = K16  + ((size_t)bh * S_PAD + sbase) * HS;

    // gload_lds staging: wave wv covers rows [wv*16, wv*16+16) per chunk.
    // Global source pre-swizzled; LINEAR LDS dest.
    int l8 = lane >> 3;
    int lg = (lane & 7) ^ l8;
    const u16* gsw = kbh + (size_t)(wv * 16 + l8) * HS + lg * 8;

    // prologue: stage chunk 0
    __builtin_amdgcn_global_load_lds(GLB(gsw),       LDS(Ks + wv * 1024),       16, 0, 0);
    __builtin_amdgcn_global_load_lds(GLB(gsw + 512), LDS(Ks + wv * 1024 + 512), 16, 0, 0);

    for (int c = 0; c < 8; ++c) {
        int s0 = sbase + c * 64;
        __syncthreads();   // staging of chunk c complete (vmcnt drained)

        // mask boundaries for this chunk's 4 s-tiles (from LDS table)
        int r4[4];
        #pragma unroll
        for (int st = 0; st < 4; ++st) r4[st] = rtab[c * 64 + st * 16 + lm];

        // QK^T: 4 s-tiles, masked, wave-uniform skip
        unsigned flags = 0;
        f32x4 lt[4];
        #pragma unroll
        for (int st = 0; st < 4; ++st) {
            int r = r4[st];
            unsigned long long bal = __ballot(r <= twmax);
            if (bal) {
                flags |= 1u << st;
                int sl = st * 16 + lm, sx = sl & 7;
                f16x8 b0 = *(const f16x8*)(Ks + sl * 64 + ((quad ^ sx) << 3));
                f16x8 b1 = *(const f16x8*)(Ks + sl * 64 + (((4 + quad) ^ sx) << 3));
                f32x4 a = (f32x4){0.f, 0.f, 0.f, 0.f};
                a = mfmah(a0, b0, a);
                a = mfmah(a1, b1, a);
                #pragma unroll
                for (int reg = 0; reg < 4; ++reg) {
                    int t = t0w + quad * 4 + reg;
                    lt[st][reg] = (t >= r) ? a[reg] : NEG_BIG;
                }
            }
        }

        if (flags) {
            // per-lane chunk max (reused by both gate and slow path)
            f32x4 mc = (f32x4){NEG_BIG, NEG_BIG, NEG_BIG, NEG_BIG};
            #pragma unroll
            for (int st = 0; st < 4; ++st)
                if ((flags >> st) & 1u)
                    #pragma unroll
                    for (int reg = 0; reg < 4; ++reg)
                        mc[reg] = fmaxf(mc[reg], lt[st][reg]);
            bool need = false;
            #pragma unroll
            for (int reg = 0; reg < 4; ++reg)
                need |= mc[reg] > mrun[reg] + 8.f;
            if (__ballot(need)) {
                // slow path: cross-lane max + rescale (log2 domain)
                #pragma unroll
                for (int off = 1; off < 16; off <<= 1)
                    #pragma unroll
                    for (int reg = 0; reg < 4; ++reg)
                        mc[reg] = fmaxf(mc[reg], __shfl_xor(mc[reg], off));
                #pragma unroll
                for (int reg = 0; reg < 4; ++reg) {
                    float mnew = fmaxf(mrun[reg], mc[reg]);
                    float alpha = exp2h(mrun[reg] - mnew);
                    lsum[reg] *= alpha;
                    #pragma unroll
                    for (int dt = 0; dt < 4; ++dt) O[dt][reg] *= alpha;
                    mrun[reg] = mnew;
                }
            }
            // fast path: P = 2^(lt - mrun); masked lt underflows to exactly 0
            #pragma unroll
            for (int st = 0; st < 4; ++st) {
                if ((flags >> st) & 1u) {
                    #pragma unroll
                    for (int reg = 0; reg < 4; ++reg) {
                        float p = exp2h(lt[st][reg] - mrun[reg]);
                        lsum[reg] += p;
                        Pw[(quad * 4 + reg) * 72 + st * 16 + lm] = f2h(p);
                    }
                } else if ((flags >> (st ^ 1)) & 1u) {
                    // zeros only needed when the PV 32-set partner is active
                    #pragma unroll
                    for (int reg = 0; reg < 4; ++reg)
                        Pw[(quad * 4 + reg) * 72 + st * 16 + lm] = 0;
                }
            }

            // P @ V chunk (skip fully-masked 32-set segments), V from L2
            #pragma unroll
            for (int kc = 0; kc < 2; ++kc) {
                if (!((flags >> (2 * kc)) & 3u)) continue;
                f16x8 afr = *(const f16x8*)(Pw + lm * 72 + kc * 32 + quad * 8);
                #pragma unroll
                for (int dt = 0; dt < 4; ++dt) {
                    size_t vo = (size_t)(dt * 16 + lm) * S_PAD + s0 + kc * 32 + quad * 8;
                    f16x8 bv = *(const f16x8*)(vb + vo);
                    O[dt] = mfmah(afr, bv, O[dt]);
                }
            }
        }

        if (c < 7) {
            __syncthreads();   // all waves done reading Ks for chunk c
            const u16* gn = gsw + (size_t)(c + 1) * 4096;
            __builtin_amdgcn_global_load_lds(GLB(gn),       LDS(Ks + wv * 1024),       16, 0, 0);
            __builtin_amdgcn_global_load_lds(GLB(gn + 512), LDS(Ks + wv * 1024 + 512), 16, 0, 0);
        }
    }

    // single cross-lane sum reduce (outside the chunk loop)
    #pragma unroll
    for (int off = 1; off < 16; off <<= 1)
        #pragma unroll
        for (int reg = 0; reg < 4; ++reg) lsum[reg] += __shfl_xor(lsum[reg], off);

    // store partials: O/l (f16) and LSE = m + log2(l) (log2 domain, f32)
    u16* Ob = Opart + ((size_t)half * 32 + bh) * T_SEQ * HS;
    float* Lb = LSEpart + ((size_t)half * 32 + bh) * T_SEQ;
    #pragma unroll
    for (int reg = 0; reg < 4; ++reg) {
        int t = t0w + quad * 4 + reg;
        float inv = lsum[reg] > 0.f ? 1.f / lsum[reg] : 0.f;
        #pragma unroll
        for (int dt = 0; dt < 4; ++dt)
            Ob[(size_t)t * HS + dt * 16 + lm] = f2h(O[dt][reg] * inv);
        if (lm == 0)
            Lb[t] = lsum[reg] > 0.f ? mrun[reg] + log2h(lsum[reg]) : NEG_BIG;
    }
}

// -------- Kernel 3b: merge two set-half partials + tail, write att16 ---------
// grid (512, 32), 256 thr: wave = one (bh,t) row, lane = dim d.
// All LSE values and the tail logit are in the log2 domain.
__global__ __launch_bounds__(256) void attn_combine(const u16* __restrict__ q16,
                                                    const u16* __restrict__ k16,
                                                    const u16* __restrict__ v16,
                                                    const u16* __restrict__ Opart,
                                                    const float* __restrict__ LSEpart,
                                                    u16* __restrict__ att16) {
    int bh = blockIdx.y;
    int wv = threadIdx.x >> 6, d = threadIdx.x & 63;
    int t = blockIdx.x * 4 + wv;
    size_t row = (size_t)bh * T_SEQ + t;

    float lse0 = LSEpart[row];
    float lse1 = LSEpart[(size_t)32 * T_SEQ + row];

    // tail: K_tail/V_tail over last (t%4)+1 positions; q16 pre-scaled (log2e)
    int len = (t & 3) + 1;
    const u16* kp = k16 + row * HS + d;
    const u16* vp = v16 + row * HS + d;
    float kt = 0.f, vt = 0.f;
    for (int j = 0; j < len; ++j) { kt += h2f(kp[-j * HS]); vt += h2f(vp[-j * HS]); }
    float tl = h2f(q16[row * HS + d]) * kt;
    #pragma unroll
    for (int off = 1; off < 64; off <<= 1) tl += __shfl_xor(tl, off);

    float mf = fmaxf(fmaxf(lse0, lse1), tl);
    float w0 = exp2h(lse0 - mf), w1 = exp2h(lse1 - mf), wt = exp2h(tl - mf);
    float inv = 1.f / (w0 + w1 + wt);
    float o0 = h2f(Opart[row * HS + d]);
    float o1 = h2f(Opart[(size_t)32 * T_SEQ * HS + row * HS + d]);
    float val = (w0 * o0 + w1 * o1 + wt * vt) * inv;

    int b_ = bh >> 4, h_ = bh & 15;
    att16[((size_t)b_ * T_SEQ + t) * C_DIM + h_ * HS + d] = f2h(val);
}

// -------- Kernel 4: out = attout @ W_proj^T, fp16 MFMA, 64x128 M-split -------
// grid 512 = 64 mt x 8 nt (mt = id&63 -> xcd = mt%8: each XCD re-reads a 1 MB
// A-slice (L2-hit across nt) and streams W (2 MB, L2-resident)).
// 2 blocks/CU (8 waves/CU). 2-phase prefetch; wave = 32x64 out.
__global__ __launch_bounds__(256) void gemm_proj16(const u16* __restrict__ a_,
                                                   const u16* __restrict__ w,
                                                   float* __restrict__ out) {
    __shared__ u16 As[2][64 * 32];     // 8 KB
    __shared__ u16 Bs[2][128 * 32];    // 16 KB
    int tid = threadIdx.x, wv = tid >> 6, lane = tid & 63;
    int lm = lane & 15, quad = lane >> 4;
    int mt = blockIdx.x & 63, nt = blockIdx.x >> 6;
    int wm = wv >> 1, wn = wv & 1;
    int m_off = wm * 32, n_off = wn * 64;

    // cooperative staging: 256 threads x 3 rounds (A 64 rows, B 128 rows)
    int srow = tid >> 2, scol = (tid & 3) * 8;
    const u16* ga  = a_ + (size_t)(mt * 64 + srow) * C_DIM + scol;
    const u16* gb0 = w  + (size_t)(nt * 128 + srow) * C_DIM + scol;
    const u16* gb1 = w  + (size_t)(nt * 128 + 64 + srow) * C_DIM + scol;
    int aoff = srow * 32 + scol, boff1 = (64 + srow) * 32 + scol;

    f32x4 acc[2][4];
    #pragma unroll
    for (int i = 0; i < 2; ++i)
        #pragma unroll
        for (int j = 0; j < 4; ++j) acc[i][j] = (f32x4){0.f, 0.f, 0.f, 0.f};

    // prologue: stage k0=0 into buffer 0
    __builtin_amdgcn_global_load_lds(GLB(ga),  LDS(&As[0][aoff]),  16, 0, 0);
    __builtin_amdgcn_global_load_lds(GLB(gb0), LDS(&Bs[0][aoff]),  16, 0, 0);
    __builtin_amdgcn_global_load_lds(GLB(gb1), LDS(&Bs[0][boff1]), 16, 0, 0);
    __syncthreads();

    for (int k0 = 0, it = 0; k0 < C_DIM; k0 += 32, ++it) {
        const u16* Ab = &As[it & 1][0];
        const u16* Bb = &Bs[it & 1][0];
        if (k0 + 32 < C_DIM) {
            int nb = (it & 1) ^ 1;
            __builtin_amdgcn_global_load_lds(GLB(ga  + k0 + 32), LDS(&As[nb][aoff]),  16, 0, 0);
            __builtin_amdgcn_global_load_lds(GLB(gb0 + k0 + 32), LDS(&Bs[nb][aoff]),  16, 0, 0);
            __builtin_amdgcn_global_load_lds(GLB(gb1 + k0 + 32), LDS(&Bs[nb][boff1]), 16, 0, 0);
        }
        f16x8 af[2], bf[4];
        #pragma unroll
        for (int i = 0; i < 2; ++i)
            af[i] = *(const f16x8*)(Ab + (m_off + i * 16 + lm) * 32 + quad * 8);
        #pragma unroll
        for (int i = 0; i < 4; ++i)
            bf[i] = *(const f16x8*)(Bb + (n_off + i * 16 + lm) * 32 + quad * 8);
        #pragma unroll
        for (int mi = 0; mi < 2; ++mi)
            #pragma unroll
            for (int ni = 0; ni < 4; ++ni)
                acc[mi][ni] = mfmah(af[mi], bf[ni], acc[mi][ni]);
        __syncthreads();
    }

    #pragma unroll
    for (int mi = 0; mi < 2; ++mi)
        #pragma unroll
        for (int ni = 0; ni < 4; ++ni) {
            int n = nt * 128 + n_off + ni * 16 + lm;
            #pragma unroll
            for (int reg = 0; reg < 4; ++reg) {
                int m = mt * 64 + m_off + mi * 16 + quad * 4 + reg;
                out[(size_t)m * C_DIM + n] = acc[mi][ni][reg];
            }
        }
}

extern "C" void kernel_launch(void* const* d_in, const int* in_sizes, int n_in,
                              void* d_out, int out_size, void* d_ws, size_t ws_size,
                              hipStream_t stream) {
    const float* x     = (const float*)d_in[0];
    const float* Wattn = (const float*)d_in[1];
    const float* Wproj = (const float*)d_in[2];
    float* out = (float*)d_out;
    char* ws = (char*)d_ws;
    // workspace layout (61.3 MB), with time-multiplexed overlays:
    //   [0, 16.78MB): x16(8MB)+wa16(6.29MB) during qkv -> Opart during attn
    u16*  Opart = (u16*)(ws + 0);            // 16,777,216 [attn partials, 2 halves]
    u16*  x16   = (u16*)(ws + 0);            //  8,388,608 (dead after gemm_qkv16)
    u16*  wa16  = (u16*)(ws + 8388608);      //  6,291,456 (dead after gemm_qkv16)
    u16*  q16   = (u16*)(ws + 16777216);     //  8,388,608 (pre-scaled, log2 dom.)
    u16*  k16   = (u16*)(ws + 25165824);     //  8,388,608
    u16*  v16   = (u16*)(ws + 33554432);     //  8,388,608
    u16*  K16   = (u16*)(ws + 41943040);     //  4,194,304
    u16*  VT16  = (u16*)(ws + 46137344);     //  4,194,304
    u16*  att16 = (u16*)(ws + 50331648);     //  8,388,608
    float* LSE  = (float*)(ws + 58720256);   //    524,288
    u16*  wp16  = (u16*)(ws + 59244544);     //  2,097,152  (end 61,341,696)

    hipLaunchKernelGGL(conv_all, dim3(8192), dim3(256), 0, stream,
                       x, Wattn, Wproj, x16, wa16, wp16);
    hipLaunchKernelGGL(gemm_qkv16, dim3(768), dim3(256), 0, stream,
                       x16, wa16, q16, k16, v16);
    hipLaunchKernelGGL(set_sums, dim3(32, 8), dim3(256), 0, stream, k16, v16, K16, VT16);
    hipLaunchKernelGGL(attn_flash16, dim3(32, 32, 2), dim3(256), 0, stream,
                       q16, K16, VT16, Opart, LSE);
    hipLaunchKernelGGL(attn_combine, dim3(512, 32), dim3(256), 0, stream,
                       q16, k16, v16, Opart, LSE, att16);
    hipLaunchKernelGGL(gemm_proj16, dim3(512), dim3(256), 0, stream, att16, wp16, out);
}